// Round 5
// baseline (1134.683 us; speedup 1.0000x reference)
//
#include <hip/hip_runtime.h>
#include <hip/hip_cooperative_groups.h>
#include <math.h>

namespace cg = cooperative_groups;

// All inputs/outputs fp32 (verified R2). R5: single cooperative kernel,
// grid.sync() between stages. R4 showed ~12 serially-dependent small
// dispatches pin total at ~400us regardless of per-kernel cost.

struct P {
    const float *tgt, *qpos, *ec, *src;
    const unsigned char* mask;
    const float *vr, *ipw, *ipb, *opw, *opb, *n1w, *n1b, *n2w, *n2b, *n3w, *n3b;
    const float *l0w, *l0b, *l1w, *l1b, *l2w, *l2b, *offw, *offb, *aww, *awb;
    const float *valw, *valb, *ojw, *ojb;
    float *qkv, *srow, *sao, *x1, *feat, *nrow, *offatr, *ca, *cao, *x2, *h1, *f2, *refxy;
    int* lxly;
    float* out;
};

__device__ __forceinline__ float block_sum256(float v, float* red) {
    int t = threadIdx.x;
    red[t] = v; __syncthreads();
    for (int st = 128; st > 0; st >>= 1) {
        if (t < st) red[t] += red[t + st];
        __syncthreads();
    }
    float r = red[0]; __syncthreads();
    return r;
}

// ---- tiled GEMM unit: 64 rows x 8 outputs. W wave-uniform -> scalar cache ----
// MI: 0 direct (stride K); 1 qkv (q/k add IN2; stride 256); 2 pool mean-of-3 (stride 256)
// MO: 0 none; 1 relu; 2 scale o<256 by 32^-0.5    MW: 0 single; 1 split at o=256
template <int K, int MI, int MO, int MW>
__device__ void gemm_unit(const float* __restrict__ IN, const float* __restrict__ IN2,
                          const float* __restrict__ W, const float* __restrict__ W2,
                          const float* __restrict__ B, const float* __restrict__ B2,
                          float* __restrict__ OUT, int O, int OG, int u, float* smem) {
    constexpr int KC = 128;
    constexpr int LDT = KC + 4;
    float* tile = smem;
    int og = u % OG, rg = u / OG;
    int o0 = og * 8, r0 = rg * 64;
    int t = threadIdx.x;
    int r = t & 63;
    int ol = __builtin_amdgcn_readfirstlane(t >> 6);
    int oa = o0 + ol, ob = o0 + 4 + ol;
    const float *Wa, *Wb;
    float Ba, Bb;
    if (MW == 1) {
        Wa = (oa < 256) ? W + (size_t)oa * K : W2 + (size_t)(oa - 256) * K;
        Wb = (ob < 256) ? W + (size_t)ob * K : W2 + (size_t)(ob - 256) * K;
        Ba = (oa < 256) ? B[oa] : B2[oa - 256];
        Bb = (ob < 256) ? B[ob] : B2[ob - 256];
    } else {
        Wa = W + (size_t)oa * K;
        Wb = W + (size_t)ob * K;
        Ba = B[oa];
        Bb = B[ob];
    }
    float acca = 0.f, accb = 0.f;
    for (int c = 0; c < K / KC; c++) {
        for (int idx = t; idx < 64 * KC; idx += 256) {
            int rr = idx >> 7, ii = idx & (KC - 1);
            int row = r0 + rr, col = c * KC + ii;
            float v;
            if (MI == 0) {
                v = IN[(size_t)row * K + col];
            } else if (MI == 1) {
                float tv = IN[row * 256 + col];
                v = (o0 < 512) ? tv + IN2[row * 256 + col] : tv;
            } else {
                v = (IN[(size_t)(3 * row) * 256 + col] +
                     IN[(size_t)(3 * row + 1) * 256 + col] +
                     IN[(size_t)(3 * row + 2) * 256 + col]) * (1.f / 3.f);
            }
            tile[rr * LDT + ii] = v;
        }
        __syncthreads();
        const float4* wa4 = (const float4*)(Wa + c * KC);
        const float4* wb4 = (const float4*)(Wb + c * KC);
        const float4* trow = (const float4*)(tile + r * LDT);
        #pragma unroll
        for (int i4 = 0; i4 < KC / 4; i4++) {
            float4 x4 = trow[i4];
            float4 a4 = wa4[i4];
            float4 b4 = wb4[i4];
            acca += x4.x * a4.x; acca += x4.y * a4.y;
            acca += x4.z * a4.z; acca += x4.w * a4.w;
            accb += x4.x * b4.x; accb += x4.y * b4.y;
            accb += x4.z * b4.z; accb += x4.w * b4.w;
        }
        __syncthreads();
    }
    acca += Ba; accb += Bb;
    if (MO == 1) { acca = fmaxf(acca, 0.f); accb = fmaxf(accb, 0.f); }
    if (MO == 2) {
        if (oa < 256) acca *= 0.17677669529663687f;
        if (ob < 256) accb *= 0.17677669529663687f;
    }
    OUT[(size_t)(r0 + r) * O + oa] = acca;
    OUT[(size_t)(r0 + r) * O + ob] = accb;
}

// ---- geometry + pos-encode: writes feat[n][256:640), refxy, lxly ----
__device__ void geompe_unit(int n, const P& p) {
    int t = threadIdx.x;
    int e = n / 3, j = n - e * 3;
    float ax = p.ec[e * 4 + 0], ay = p.ec[e * 4 + 1];
    float bx = p.ec[e * 4 + 2], by = p.ec[e * 4 + 3];
    float tj = 0.5f * (float)j;
    float dx = bx - ax, dy = by - ay;
    float ptx = __fadd_rn(ax, __fmul_rn(tj, dx));
    float pty = __fadd_rn(ay, __fmul_rn(tj, dy));
    float cxf = floorf(ptx), cyf = floorf(pty);
    int minx = max((int)cxf - 128, 0); if (minx + 256 > 2048) minx = 2048 - 256;
    int miny = max((int)cyf - 128, 0); if (miny + 256 > 2048) miny = 2048 - 256;
    float fminx = (float)minx, fminy = (float)miny;
    float tlx, thx, tly, thy;
    if (dx == 0.f) { tlx = 0.f; thx = 1.f; }
    else { float u1 = (fminx - ax) / dx, u2 = (fminx + 256.f - ax) / dx; tlx = fminf(u1, u2); thx = fmaxf(u1, u2); }
    if (dy == 0.f) { tly = 0.f; thy = 1.f; }
    else { float u1 = (fminy - ay) / dy, u2 = (fminy + 256.f - ay) / dy; tly = fminf(u1, u2); thy = fmaxf(u1, u2); }
    float t0 = fmaxf(fmaxf(tlx, tly), 0.f);
    float t1 = fmaxf(fminf(fminf(thx, thy), 1.f), t0);
    float pxs[3], pys[3];
    pxs[0] = __fadd_rn(ax, __fmul_rn(t0, dx)); pys[0] = __fadd_rn(ay, __fmul_rn(t0, dy));
    pxs[1] = __fadd_rn(ax, __fmul_rn(t1, dx)); pys[1] = __fadd_rn(ay, __fmul_rn(t1, dy));
    pxs[2] = cxf; pys[2] = cyf;
    float* fg = p.feat + (size_t)n * 640;
    #pragma unroll
    for (int rep = 0; rep < 2; rep++) {
        int idx = rep * 256 + t;
        if (idx < 384) {
            int jj = idx >> 7, tt = idx & 127, i = tt & 63, kk = i >> 1;
            float invd = __expf(-(float)kk * (9.210340371976184f / 32.f));  // 10000^(-kk/32)
            float vv = (tt < 64) ? pys[jj] : pxs[jj];
            float pp = vv * invd;
            fg[256 + idx] = (i & 1) ? __cosf(pp) : __sinf(pp);
        }
    }
    if (t == 0) {
        p.refxy[n * 2 + 0] = (cxf - fminx) * (1.f / 256.f);
        p.refxy[n * 2 + 1] = (cyf - fminy) * (1.f / 256.f);
        p.lxly[n * 8 + 0] = (int)rintf(fminx * 0.125f);
        p.lxly[n * 8 + 1] = (int)rintf(fminx * 0.0625f);
        p.lxly[n * 8 + 2] = (int)rintf(fminx * 0.03125f);
        p.lxly[n * 8 + 3] = (int)rintf(fminx * 0.015625f);
        p.lxly[n * 8 + 4] = (int)rintf(fminy * 0.125f);
        p.lxly[n * 8 + 5] = (int)rintf(fminy * 0.0625f);
        p.lxly[n * 8 + 6] = (int)rintf(fminy * 0.03125f);
        p.lxly[n * 8 + 7] = (int)rintf(fminy * 0.015625f);
    }
}

// ---- attention core (per edge) ----
__device__ void attn_unit(int e, const P& p, float* smem) {
    int t = threadIdx.x;
    float* sq = smem;           // 256
    float* sS = smem + 256;     // 1024
    float* smax = smem + 1280;  // 8
    float* ssum = smem + 1288;  // 8
    sq[t] = p.qkv[e * 768 + t];
    __syncthreads();
    for (int it = 0; it < 4; it++) {
        int idx = it * 256 + t, h = idx >> 7, f = idx & 127;
        const float* kf = p.qkv + f * 768 + 256 + h * 32;
        const float* qh = sq + h * 32;
        float s = 0.f;
        for (int d = 0; d < 32; d++) s += qh[d] * kf[d];
        sS[idx] = s;
    }
    __syncthreads();
    if (t < 8) {
        float m = -1e30f;
        for (int f = 0; f < 128; f++) m = fmaxf(m, sS[t * 128 + f]);
        smax[t] = m;
    }
    __syncthreads();
    for (int it = 0; it < 4; it++) {
        int idx = it * 256 + t, h = idx >> 7;
        sS[idx] = __expf(sS[idx] - smax[h]);
    }
    __syncthreads();
    if (t < 8) {
        float s = 0.f;
        for (int f = 0; f < 128; f++) s += sS[t * 128 + f];
        ssum[t] = 1.f / s;
    }
    __syncthreads();
    {
        int h = t >> 5, d = t & 31;
        float acc = 0.f;
        for (int f = 0; f < 128; f++) acc += sS[h * 128 + f] * p.qkv[f * 768 + 512 + h * 32 + d];
        p.srow[e * 256 + t] = acc * ssum[h];
    }
    __syncthreads();
}

// ---- norm2 + feat[0:256) (per edge) ----
__device__ void norm2feat_unit(int e, const P& p, float* smem) {
    int t = threadIdx.x;
    float acc = p.sao[e * 256 + t] + p.tgt[e * 256 + t];
    float mean = block_sum256(acc, smem) * (1.f / 256.f);
    float d0 = acc - mean;
    float var = block_sum256(d0 * d0, smem) * (1.f / 256.f);
    float xln = d0 * rsqrtf(var + 1e-5f) * p.n2w[t] + p.n2b[t];
    p.x1[e * 256 + t] = xln;
    float fv = xln + p.qpos[e * 256 + t];
    p.feat[(size_t)(3 * e) * 640 + t] = fv;
    p.feat[(size_t)(3 * e + 1) * 640 + t] = fv;
    p.feat[(size_t)(3 * e + 2) * 640 + t] = fv;
}

// ---- sampling unit (per n,h): softmax+loc in-block, linearity-fused ----
__device__ void sample_unit(int u, const P& p, float* smem) {
    int n = u >> 3, h = u & 7, t = threadIdx.x;
    float* cw   = smem;           // 64
    int*   cgi  = (int*)(smem + 64); // 64
    float* agg  = smem + 128;     // 256
    float* sl   = smem + 384;     // 16
    float* sred = smem + 400;     // 2
    float* pagg = smem + 402;     // 256
    if (t < 16) sl[t] = p.offatr[n * 384 + 256 + h * 16 + t];
    __syncthreads();
    if (t == 0) {
        float m = -1e30f;
        for (int i = 0; i < 16; i++) m = fmaxf(m, sl[i]);
        float s = 0.f;
        for (int i = 0; i < 16; i++) s += __expf(sl[i] - m);
        sred[0] = m; sred[1] = 1.f / s;
    }
    __syncthreads();
    if (t < 64) {
        int l = t >> 4, pp = (t >> 2) & 3, tap = t & 3;
        int s = 32 >> l;
        int wl = 256 >> l;
        const int img_starts[4] = {0, 65536, 81920, 86016};
        float a = __expf(sl[l * 4 + pp] - sred[0]) * sred[1];
        float slv = (float)s;
        float gx = p.refxy[n * 2 + 0] * p.vr[l * 2 + 0] + p.offatr[n * 384 + h * 32 + l * 8 + pp * 2 + 0] / slv;
        float gy = p.refxy[n * 2 + 1] * p.vr[l * 2 + 1] + p.offatr[n * 384 + h * 32 + l * 8 + pp * 2 + 1] / slv;
        float px = gx * slv - 0.5f, py = gy * slv - 0.5f;
        float x0 = floorf(px), y0 = floorf(py);
        float fx = px - x0, fy = py - y0;
        int xi = (int)x0 + (tap & 1), yi = (int)y0 + (tap >> 1);
        float wt = ((tap & 1) ? fx : (1.f - fx)) * ((tap >> 1) ? fy : (1.f - fy));
        int g = -1;
        if (xi >= 0 && xi < s && yi >= 0 && yi < s) {
            int col = p.lxly[n * 8 + l] + xi;
            int row = p.lxly[n * 8 + 4 + l] + yi;
            g = img_starts[l] + row * wl + col;
            if (p.mask[g]) g = -1;
        }
        cw[t] = a * wt;
        cgi[t] = g;
    }
    __syncthreads();
    float acc = 0.f, csum = 0.f;
    for (int tp = 0; tp < 64; tp++) {
        int g = cgi[tp];
        if (g >= 0) {
            acc += cw[tp] * p.src[(size_t)g * 256 + t];
            csum += cw[tp];
        }
    }
    agg[t] = acc;
    __syncthreads();
    {
        int o = t & 31, qtr = t >> 5;
        const float* w = p.valw + (size_t)(h * 32 + o) * 256 + qtr * 32;
        const float* ag = agg + qtr * 32;
        float pv = 0.f;
        for (int i = 0; i < 32; i++) pv += ag[i] * w[i];
        pagg[o * 8 + qtr] = pv;
    }
    __syncthreads();
    if (t < 32) {
        float o = 0.f;
        for (int qtr = 0; qtr < 8; qtr++) o += pagg[t * 8 + qtr];
        p.ca[n * 256 + h * 32 + t] = o + csum * p.valb[h * 32 + t];
    }
    __syncthreads();
}

// ---- LN(a+b) per edge ----
__device__ void norm_unit(int e, const float* a, const float* b, const float* nw,
                          const float* nb, float* out, float* smem) {
    int t = threadIdx.x;
    float acc = a[e * 256 + t] + b[e * 256 + t];
    float mean = block_sum256(acc, smem) * (1.f / 256.f);
    float d0 = acc - mean;
    float var = block_sum256(d0 * d0, smem) * (1.f / 256.f);
    out[e * 256 + t] = d0 * rsqrtf(var + 1e-5f) * nw[t] + nb[t];
}

__global__ __launch_bounds__(256, 2) void mega(P p) {
    __shared__ __align__(16) float smem[8448];  // 33792 B -> 2 blocks/CU
    cg::grid_group grid = cg::this_grid();
    const int bid = blockIdx.x, G = gridDim.x;

    // S1: qkv gemm (192) + geometry/pos-encode (384)
    for (int u = bid; u < 576; u += G) {
        if (u < 192) gemm_unit<256, 1, 2, 0>(p.tgt, p.qpos, p.ipw, nullptr, p.ipb, nullptr, p.qkv, 768, 96, u, smem);
        else geompe_unit(u - 192, p);
    }
    grid.sync();
    // S2: attention
    for (int u = bid; u < 128; u += G) attn_unit(u, p, smem);
    grid.sync();
    // S3: out-proj
    for (int u = bid; u < 64; u += G) gemm_unit<256, 0, 0, 0>(p.srow, nullptr, p.opw, nullptr, p.opb, nullptr, p.sao, 256, 32, u, smem);
    grid.sync();
    // S4: norm2 + feat head
    for (int u = bid; u < 128; u += G) norm2feat_unit(u, p, smem);
    grid.sync();
    // S5: nq = feat @ lin0
    for (int u = bid; u < 192; u += G) gemm_unit<640, 0, 0, 0>(p.feat, nullptr, p.l0w, nullptr, p.l0b, nullptr, p.nrow, 256, 32, u, smem);
    grid.sync();
    // S6: off + attw (split weights)
    for (int u = bid; u < 288; u += G) gemm_unit<256, 0, 0, 1>(p.nrow, nullptr, p.offw, p.aww, p.offb, p.awb, p.offatr, 384, 48, u, smem);
    grid.sync();
    // S7: deformable sampling
    for (int u = bid; u < 3072; u += G) sample_unit(u, p, smem);
    grid.sync();
    // S8: pool + oproj
    for (int u = bid; u < 64; u += G) gemm_unit<256, 2, 0, 0>(p.ca, nullptr, p.ojw, nullptr, p.ojb, nullptr, p.cao, 256, 32, u, smem);
    grid.sync();
    // S9: norm1
    for (int u = bid; u < 128; u += G) norm_unit(u, p.x1, p.cao, p.n1w, p.n1b, p.x2, smem);
    grid.sync();
    // S10: ffn1 (relu)
    for (int u = bid; u < 256; u += G) gemm_unit<256, 0, 1, 0>(p.x2, nullptr, p.l1w, nullptr, p.l1b, nullptr, p.h1, 1024, 128, u, smem);
    grid.sync();
    // S11: ffn2
    for (int u = bid; u < 64; u += G) gemm_unit<1024, 0, 0, 0>(p.h1, nullptr, p.l2w, nullptr, p.l2b, nullptr, p.f2, 256, 32, u, smem);
    grid.sync();
    // S12: norm3 -> out
    for (int u = bid; u < 128; u += G) norm_unit(u, p.x2, p.f2, p.n3w, p.n3b, p.out, smem);
}

extern "C" void kernel_launch(void* const* d_in, const int* in_sizes, int n_in,
                              void* d_out, int out_size, void* d_ws, size_t ws_size,
                              hipStream_t stream) {
    (void)in_sizes; (void)n_in; (void)out_size; (void)ws_size;
    P p;
    p.tgt  = (const float*)d_in[0];
    p.qpos = (const float*)d_in[1];
    p.ec   = (const float*)d_in[2];
    p.src  = (const float*)d_in[3];
    p.mask = (const unsigned char*)d_in[4];
    p.vr   = (const float*)d_in[5];
    p.ipw  = (const float*)d_in[6];
    p.ipb  = (const float*)d_in[7];
    p.opw  = (const float*)d_in[8];
    p.opb  = (const float*)d_in[9];
    p.n1w  = (const float*)d_in[10];
    p.n1b  = (const float*)d_in[11];
    p.n2w  = (const float*)d_in[12];
    p.n2b  = (const float*)d_in[13];
    p.n3w  = (const float*)d_in[14];
    p.n3b  = (const float*)d_in[15];
    p.l0w  = (const float*)d_in[16];
    p.l0b  = (const float*)d_in[17];
    p.l1w  = (const float*)d_in[18];
    p.l1b  = (const float*)d_in[19];
    p.l2w  = (const float*)d_in[20];
    p.l2b  = (const float*)d_in[21];
    p.offw = (const float*)d_in[22];
    p.offb = (const float*)d_in[23];
    p.aww  = (const float*)d_in[24];
    p.awb  = (const float*)d_in[25];
    p.valw = (const float*)d_in[26];
    p.valb = (const float*)d_in[27];
    p.ojw  = (const float*)d_in[28];
    p.ojb  = (const float*)d_in[29];

    float* ws = (float*)d_ws;
    p.qkv    = ws;             // 98304
    p.srow   = ws + 98304;     // 32768
    p.sao    = ws + 131072;    // 32768
    p.x1     = ws + 163840;    // 32768
    p.feat   = ws + 196608;    // 245760
    p.nrow   = ws + 442368;    // 98304
    p.offatr = ws + 540672;    // 147456
    p.ca     = ws + 688128;    // 98304
    p.cao    = ws + 786432;    // 32768
    p.x2     = ws + 819200;    // 32768
    p.h1     = ws + 851968;    // 131072
    p.f2     = ws + 983040;    // 32768
    p.refxy  = ws + 1015808;   // 768
    p.lxly   = (int*)(ws + 1016576);
    p.out    = (float*)d_out;

    void* args[] = { (void*)&p };
    hipLaunchCooperativeKernel(reinterpret_cast<const void*>(&mega),
                               dim3(512), dim3(256), args, 0, stream);
}

// Round 6
// 383.095 us; speedup vs baseline: 2.9619x; 2.9619x over previous
//
#include <hip/hip_runtime.h>
#include <math.h>

// All inputs/outputs fp32 (verified R2).
// R6: 6-stage pipeline. R5 proved cg::grid.sync costs ~80us/sync (dead end)
// and calibrated harness fixed overhead ~194us. R4's 403us = 194 + ~209us of
// 12 serial latency-bound stages. This round cuts the chain to 6 stages via
// per-edge fusion with pre-transposed weights (coalesced matvec weight reads).

__device__ __forceinline__ float block_sum256(float v, float* red) {
    int t = threadIdx.x;
    red[t] = v; __syncthreads();
    for (int st = 128; st > 0; st >>= 1) {
        if (t < st) red[t] += red[t + st];
        __syncthreads();
    }
    float r = red[0]; __syncthreads();
    return r;
}

// ---- tiled GEMM unit (R4-verified): 64 rows x 8 outputs, W rows scalar-cached ----
// MI: 0 direct (stride K); 1 qkv (o<512 adds IN2; stride 256)
// MO: 0 none; 2 scale o<256 by 32^-0.5    MW: 0 single; 1 split at o=256
template <int K, int MI, int MO, int MW>
__device__ void gemm_unit(const float* __restrict__ IN, const float* __restrict__ IN2,
                          const float* __restrict__ W, const float* __restrict__ W2,
                          const float* __restrict__ B, const float* __restrict__ B2,
                          float* __restrict__ OUT, int O, int OG, int u, float* smem) {
    constexpr int KC = 128;
    constexpr int LDT = KC + 4;
    float* tile = smem;
    int og = u % OG, rg = u / OG;
    int o0 = og * 8, r0 = rg * 64;
    int t = threadIdx.x;
    int r = t & 63;
    int ol = __builtin_amdgcn_readfirstlane(t >> 6);
    int oa = o0 + ol, ob = o0 + 4 + ol;
    const float *Wa, *Wb;
    float Ba, Bb;
    if (MW == 1) {
        Wa = (oa < 256) ? W + (size_t)oa * K : W2 + (size_t)(oa - 256) * K;
        Wb = (ob < 256) ? W + (size_t)ob * K : W2 + (size_t)(ob - 256) * K;
        Ba = (oa < 256) ? B[oa] : B2[oa - 256];
        Bb = (ob < 256) ? B[ob] : B2[ob - 256];
    } else {
        Wa = W + (size_t)oa * K;
        Wb = W + (size_t)ob * K;
        Ba = B[oa];
        Bb = B[ob];
    }
    float acca = 0.f, accb = 0.f;
    for (int c = 0; c < K / KC; c++) {
        for (int idx = t; idx < 64 * KC; idx += 256) {
            int rr = idx >> 7, ii = idx & (KC - 1);
            int row = r0 + rr, col = c * KC + ii;
            float v;
            if (MI == 0) {
                v = IN[(size_t)row * K + col];
            } else {
                float tv = IN[row * 256 + col];
                v = (o0 < 512) ? tv + IN2[row * 256 + col] : tv;
            }
            tile[rr * LDT + ii] = v;
        }
        __syncthreads();
        const float4* wa4 = (const float4*)(Wa + c * KC);
        const float4* wb4 = (const float4*)(Wb + c * KC);
        const float4* trow = (const float4*)(tile + r * LDT);
        #pragma unroll
        for (int i4 = 0; i4 < KC / 4; i4++) {
            float4 x4 = trow[i4];
            float4 a4 = wa4[i4];
            float4 b4 = wb4[i4];
            acca += x4.x * a4.x; acca += x4.y * a4.y;
            acca += x4.z * a4.z; acca += x4.w * a4.w;
            accb += x4.x * b4.x; accb += x4.y * b4.y;
            accb += x4.z * b4.z; accb += x4.w * b4.w;
        }
        __syncthreads();
    }
    acca += Ba; accb += Bb;
    if (MO == 2) {
        if (oa < 256) acca *= 0.17677669529663687f;
        if (ob < 256) accb *= 0.17677669529663687f;
    }
    OUT[(size_t)(r0 + r) * O + oa] = acca;
    OUT[(size_t)(r0 + r) * O + ob] = accb;
}

// ---- 32x32 transpose unit: out[c][r] = in[r][c] ----
__device__ void transpose_unit(const float* __restrict__ in, float* __restrict__ out,
                               int R, int C, int u, float* smem) {
    int TC = C >> 5;
    int tc = u % TC, tr = u / TC;
    int t = threadIdx.x;
    int lr = t >> 5, lc = t & 31;
    #pragma unroll
    for (int rr = 0; rr < 32; rr += 8) {
        smem[(rr + lr) * 33 + lc] = in[(size_t)(tr * 32 + rr + lr) * C + tc * 32 + lc];
    }
    __syncthreads();
    #pragma unroll
    for (int rr = 0; rr < 32; rr += 8) {
        out[(size_t)(tc * 32 + rr + lr) * R + tr * 32 + lc] = smem[lc * 33 + rr + lr];
    }
    __syncthreads();
}

// ---------------- L1: qkv gemm + weight transposes ----------------
// grid 896: u<192 qkv gemm; then opw(64), ojw(64), valw(64), l1w(256), l2w(256)
__global__ __launch_bounds__(256) void k_prep(const float* __restrict__ tgt,
                                              const float* __restrict__ qpos,
                                              const float* __restrict__ ipw,
                                              const float* __restrict__ ipb,
                                              const float* __restrict__ opw,
                                              const float* __restrict__ ojw,
                                              const float* __restrict__ valw,
                                              const float* __restrict__ l1w,
                                              const float* __restrict__ l2w,
                                              float* __restrict__ qkv,
                                              float* __restrict__ opwT,
                                              float* __restrict__ ojwT,
                                              float* __restrict__ valwT,
                                              float* __restrict__ l1wT,
                                              float* __restrict__ l2wT) {
    __shared__ __align__(16) float smem[8448];
    int u = blockIdx.x;
    if (u < 192) {
        gemm_unit<256, 1, 2, 0>(tgt, qpos, ipw, nullptr, ipb, nullptr, qkv, 768, 96, u, smem);
    } else if (u < 256) {
        transpose_unit(opw, opwT, 256, 256, u - 192, smem);
    } else if (u < 320) {
        transpose_unit(ojw, ojwT, 256, 256, u - 256, smem);
    } else if (u < 384) {
        transpose_unit(valw, valwT, 256, 256, u - 320, smem);
    } else if (u < 640) {
        transpose_unit(l1w, l1wT, 1024, 256, u - 384, smem);
    } else {
        transpose_unit(l2w, l2wT, 256, 1024, u - 640, smem);
    }
}

// ---------------- L2: attn + out-proj + norm2 + feat head + geom/pe ----------------
// grid 128 (per edge), block 256
__global__ __launch_bounds__(256) void k_edge(const float* __restrict__ qkv,
                                              const float* __restrict__ tgt,
                                              const float* __restrict__ qpos,
                                              const float* __restrict__ opwT,
                                              const float* __restrict__ opb,
                                              const float* __restrict__ n2w,
                                              const float* __restrict__ n2b,
                                              const float* __restrict__ ec,
                                              float* __restrict__ x1,
                                              float* __restrict__ feat,
                                              float* __restrict__ refxy,
                                              int* __restrict__ lxly) {
    int e = blockIdx.x, t = threadIdx.x;
    __shared__ float sq[256], sS[1024], smax[8], ssum[8], srow[256], red[256];
    // ---- attention ----
    sq[t] = qkv[e * 768 + t];
    __syncthreads();
    for (int it = 0; it < 4; it++) {
        int idx = it * 256 + t, h = idx >> 7, f = idx & 127;
        const float* kf = qkv + f * 768 + 256 + h * 32;
        const float* qh = sq + h * 32;
        float s = 0.f;
        for (int d = 0; d < 32; d++) s += qh[d] * kf[d];
        sS[idx] = s;
    }
    __syncthreads();
    if (t < 8) {
        float m = -1e30f;
        for (int f = 0; f < 128; f++) m = fmaxf(m, sS[t * 128 + f]);
        smax[t] = m;
    }
    __syncthreads();
    for (int it = 0; it < 4; it++) {
        int idx = it * 256 + t, h = idx >> 7;
        sS[idx] = __expf(sS[idx] - smax[h]);
    }
    __syncthreads();
    if (t < 8) {
        float s = 0.f;
        for (int f = 0; f < 128; f++) s += sS[t * 128 + f];
        ssum[t] = 1.f / s;
    }
    __syncthreads();
    {
        int h = t >> 5, d = t & 31;
        float acc = 0.f;
        for (int f = 0; f < 128; f++) acc += sS[h * 128 + f] * qkv[f * 768 + 512 + h * 32 + d];
        srow[t] = acc * ssum[h];
    }
    __syncthreads();
    // ---- out-proj (coalesced via opwT) + residual + norm2 ----
    float acc = opb[t] + tgt[e * 256 + t];
    #pragma unroll 8
    for (int i = 0; i < 256; i++) acc += srow[i] * opwT[(size_t)i * 256 + t];
    float mean = block_sum256(acc, red) * (1.f / 256.f);
    float d0 = acc - mean;
    float var = block_sum256(d0 * d0, red) * (1.f / 256.f);
    float xln = d0 * rsqrtf(var + 1e-5f) * n2w[t] + n2b[t];
    x1[e * 256 + t] = xln;
    float fv = xln + qpos[e * 256 + t];
    feat[(size_t)(3 * e + 0) * 640 + t] = fv;
    feat[(size_t)(3 * e + 1) * 640 + t] = fv;
    feat[(size_t)(3 * e + 2) * 640 + t] = fv;
    // ---- geometry + pos-encode for the 3 points of this edge ----
    float ax = ec[e * 4 + 0], ay = ec[e * 4 + 1];
    float bx = ec[e * 4 + 2], by = ec[e * 4 + 3];
    float dx = bx - ax, dy = by - ay;
    for (int j = 0; j < 3; j++) {
        int n = 3 * e + j;
        float tj = 0.5f * (float)j;
        float ptx = __fadd_rn(ax, __fmul_rn(tj, dx));
        float pty = __fadd_rn(ay, __fmul_rn(tj, dy));
        float cxf = floorf(ptx), cyf = floorf(pty);
        int minx = max((int)cxf - 128, 0); if (minx + 256 > 2048) minx = 2048 - 256;
        int miny = max((int)cyf - 128, 0); if (miny + 256 > 2048) miny = 2048 - 256;
        float fminx = (float)minx, fminy = (float)miny;
        float tlx, thx, tly, thy;
        if (dx == 0.f) { tlx = 0.f; thx = 1.f; }
        else { float u1 = (fminx - ax) / dx, u2 = (fminx + 256.f - ax) / dx; tlx = fminf(u1, u2); thx = fmaxf(u1, u2); }
        if (dy == 0.f) { tly = 0.f; thy = 1.f; }
        else { float u1 = (fminy - ay) / dy, u2 = (fminy + 256.f - ay) / dy; tly = fminf(u1, u2); thy = fmaxf(u1, u2); }
        float t0 = fmaxf(fmaxf(tlx, tly), 0.f);
        float t1 = fmaxf(fminf(fminf(thx, thy), 1.f), t0);
        float pxs[3], pys[3];
        pxs[0] = __fadd_rn(ax, __fmul_rn(t0, dx)); pys[0] = __fadd_rn(ay, __fmul_rn(t0, dy));
        pxs[1] = __fadd_rn(ax, __fmul_rn(t1, dx)); pys[1] = __fadd_rn(ay, __fmul_rn(t1, dy));
        pxs[2] = cxf; pys[2] = cyf;
        float* fg = feat + (size_t)n * 640 + 256;
        #pragma unroll
        for (int rep = 0; rep < 2; rep++) {
            int idx = rep * 256 + t;
            if (idx < 384) {
                int jj = idx >> 7, tt = idx & 127, i = tt & 63, kk = i >> 1;
                float invd = __expf(-(float)kk * (9.210340371976184f / 32.f));  // 10000^(-kk/32)
                float vv = (tt < 64) ? pys[jj] : pxs[jj];
                float pp = vv * invd;
                fg[idx] = (i & 1) ? __cosf(pp) : __sinf(pp);
            }
        }
        if (t == 0) {
            refxy[n * 2 + 0] = (cxf - fminx) * (1.f / 256.f);
            refxy[n * 2 + 1] = (cyf - fminy) * (1.f / 256.f);
            lxly[n * 8 + 0] = (int)rintf(fminx * 0.125f);
            lxly[n * 8 + 1] = (int)rintf(fminx * 0.0625f);
            lxly[n * 8 + 2] = (int)rintf(fminx * 0.03125f);
            lxly[n * 8 + 3] = (int)rintf(fminx * 0.015625f);
            lxly[n * 8 + 4] = (int)rintf(fminy * 0.125f);
            lxly[n * 8 + 5] = (int)rintf(fminy * 0.0625f);
            lxly[n * 8 + 6] = (int)rintf(fminy * 0.03125f);
            lxly[n * 8 + 7] = (int)rintf(fminy * 0.015625f);
        }
    }
}

// ---------------- L3/L4: standalone gemms (R4-verified) ----------------
template <int K, int MI, int MO, int MW>
__global__ __launch_bounds__(256) void k_gemm(const float* __restrict__ IN,
                                              const float* __restrict__ IN2,
                                              const float* __restrict__ W,
                                              const float* __restrict__ W2,
                                              const float* __restrict__ B,
                                              const float* __restrict__ B2,
                                              float* __restrict__ OUT,
                                              int O, int OG) {
    __shared__ __align__(16) float smem[8448];
    gemm_unit<K, MI, MO, MW>(IN, IN2, W, W2, B, B2, OUT, O, OG, blockIdx.x, smem);
}

// ---------------- L5: deformable sampling (linearity-fused, valwT) ----------------
// grid N*H=3072, block 256
__global__ __launch_bounds__(256) void k_sample(const float* __restrict__ offatr,
                                                const float* __restrict__ refxy,
                                                const float* __restrict__ vr,
                                                const int* __restrict__ lxly,
                                                const float* __restrict__ src,
                                                const unsigned char* __restrict__ mask,
                                                const float* __restrict__ valwT,
                                                const float* __restrict__ valb,
                                                float* __restrict__ ca) {
    int n = blockIdx.x >> 3, h = blockIdx.x & 7, t = threadIdx.x;
    __shared__ float cw[64];
    __shared__ int cg[64];
    __shared__ float agg[256];
    __shared__ float sl[16], sred[2];
    __shared__ float pagg[32 * 8];
    if (t < 16) sl[t] = offatr[n * 384 + 256 + h * 16 + t];
    __syncthreads();
    if (t == 0) {
        float m = -1e30f;
        for (int i = 0; i < 16; i++) m = fmaxf(m, sl[i]);
        float s = 0.f;
        for (int i = 0; i < 16; i++) s += __expf(sl[i] - m);
        sred[0] = m; sred[1] = 1.f / s;
    }
    __syncthreads();
    if (t < 64) {
        int l = t >> 4, pp = (t >> 2) & 3, tap = t & 3;
        int s = 32 >> l;
        int wl = 256 >> l;
        const int img_starts[4] = {0, 65536, 81920, 86016};
        float a = __expf(sl[l * 4 + pp] - sred[0]) * sred[1];
        float slv = (float)s;
        float gx = refxy[n * 2 + 0] * vr[l * 2 + 0] + offatr[n * 384 + h * 32 + l * 8 + pp * 2 + 0] / slv;
        float gy = refxy[n * 2 + 1] * vr[l * 2 + 1] + offatr[n * 384 + h * 32 + l * 8 + pp * 2 + 1] / slv;
        float px = gx * slv - 0.5f, py = gy * slv - 0.5f;
        float x0 = floorf(px), y0 = floorf(py);
        float fx = px - x0, fy = py - y0;
        int xi = (int)x0 + (tap & 1), yi = (int)y0 + (tap >> 1);
        float wt = ((tap & 1) ? fx : (1.f - fx)) * ((tap >> 1) ? fy : (1.f - fy));
        int g = -1;
        if (xi >= 0 && xi < s && yi >= 0 && yi < s) {
            int col = lxly[n * 8 + l] + xi;
            int row = lxly[n * 8 + 4 + l] + yi;
            g = img_starts[l] + row * wl + col;
            if (mask[g]) g = -1;  // masked rows zeroed (incl. bias)
        }
        cw[t] = a * wt;
        cg[t] = g;
    }
    __syncthreads();
    float acc = 0.f, csum = 0.f;
    for (int tp = 0; tp < 64; tp++) {
        int g = cg[tp];
        if (g >= 0) {
            acc += cw[tp] * src[(size_t)g * 256 + t];
            csum += cw[tp];
        }
    }
    agg[t] = acc;
    __syncthreads();
    // value proj via valwT: coalesced
    {
        int o = t & 31, qtr = t >> 5;
        float pv = 0.f;
        #pragma unroll
        for (int i = 0; i < 32; i++) {
            int ii = qtr * 32 + i;
            pv += agg[ii] * valwT[(size_t)ii * 256 + h * 32 + o];
        }
        pagg[o * 8 + qtr] = pv;
    }
    __syncthreads();
    if (t < 32) {
        float o = 0.f;
        for (int qtr = 0; qtr < 8; qtr++) o += pagg[t * 8 + qtr];
        ca[n * 256 + h * 32 + t] = o + csum * valb[h * 32 + t];
    }
}

// ---------------- L6: pool + oproj + norm1 + ffn1 + ffn2 + norm3 ----------------
// grid 128 (per edge), block 256
__global__ __launch_bounds__(256) void k_tail(const float* __restrict__ ca,
                                              const float* __restrict__ x1,
                                              const float* __restrict__ ojwT,
                                              const float* __restrict__ ojb,
                                              const float* __restrict__ n1w,
                                              const float* __restrict__ n1b,
                                              const float* __restrict__ l1wT,
                                              const float* __restrict__ l1b,
                                              const float* __restrict__ l2wT,
                                              const float* __restrict__ l2b,
                                              const float* __restrict__ n3w,
                                              const float* __restrict__ n3b,
                                              float* __restrict__ out) {
    int e = blockIdx.x, t = threadIdx.x;
    __shared__ float row[256], red[256], x2s[256], h1s[1024];
    row[t] = (ca[(3 * e) * 256 + t] + ca[(3 * e + 1) * 256 + t] + ca[(3 * e + 2) * 256 + t]) * (1.f / 3.f);
    __syncthreads();
    // oproj + residual + norm1
    {
        float acc = ojb[t] + x1[e * 256 + t];
        #pragma unroll 8
        for (int i = 0; i < 256; i++) acc += row[i] * ojwT[(size_t)i * 256 + t];
        float mean = block_sum256(acc, red) * (1.f / 256.f);
        float d0 = acc - mean;
        float var = block_sum256(d0 * d0, red) * (1.f / 256.f);
        x2s[t] = d0 * rsqrtf(var + 1e-5f) * n1w[t] + n1b[t];
    }
    __syncthreads();
    // ffn1 (4 outputs/thread, interleaved for ILP)
    {
        float a0 = l1b[t], a1 = l1b[256 + t], a2 = l1b[512 + t], a3 = l1b[768 + t];
        #pragma unroll 4
        for (int i = 0; i < 256; i++) {
            float xv = x2s[i];
            const float* wr = l1wT + (size_t)i * 1024;
            a0 += xv * wr[t];
            a1 += xv * wr[t + 256];
            a2 += xv * wr[t + 512];
            a3 += xv * wr[t + 768];
        }
        h1s[t] = fmaxf(a0, 0.f);
        h1s[t + 256] = fmaxf(a1, 0.f);
        h1s[t + 512] = fmaxf(a2, 0.f);
        h1s[t + 768] = fmaxf(a3, 0.f);
    }
    __syncthreads();
    // ffn2 + residual + norm3 (4 partial accs for ILP)
    {
        float p0 = 0.f, p1 = 0.f, p2 = 0.f, p3 = 0.f;
        #pragma unroll 4
        for (int i = 0; i < 256; i++) {
            p0 += h1s[i] * l2wT[(size_t)i * 256 + t];
            p1 += h1s[i + 256] * l2wT[(size_t)(i + 256) * 256 + t];
            p2 += h1s[i + 512] * l2wT[(size_t)(i + 512) * 256 + t];
            p3 += h1s[i + 768] * l2wT[(size_t)(i + 768) * 256 + t];
        }
        float acc = l2b[t] + x2s[t] + ((p0 + p1) + (p2 + p3));
        float mean = block_sum256(acc, red) * (1.f / 256.f);
        float d0 = acc - mean;
        float var = block_sum256(d0 * d0, red) * (1.f / 256.f);
        out[e * 256 + t] = d0 * rsqrtf(var + 1e-5f) * n3w[t] + n3b[t];
    }
}

extern "C" void kernel_launch(void* const* d_in, const int* in_sizes, int n_in,
                              void* d_out, int out_size, void* d_ws, size_t ws_size,
                              hipStream_t stream) {
    (void)in_sizes; (void)n_in; (void)out_size; (void)ws_size;
    const float* tgt  = (const float*)d_in[0];
    const float* qpos = (const float*)d_in[1];
    const float* ec   = (const float*)d_in[2];
    const float* src  = (const float*)d_in[3];
    const unsigned char* mask = (const unsigned char*)d_in[4];
    const float* vr   = (const float*)d_in[5];
    const float* ipw  = (const float*)d_in[6];
    const float* ipb  = (const float*)d_in[7];
    const float* opw  = (const float*)d_in[8];
    const float* opb  = (const float*)d_in[9];
    const float* n1w  = (const float*)d_in[10];
    const float* n1b  = (const float*)d_in[11];
    const float* n2w  = (const float*)d_in[12];
    const float* n2b  = (const float*)d_in[13];
    const float* n3w  = (const float*)d_in[14];
    const float* n3b  = (const float*)d_in[15];
    const float* l0w  = (const float*)d_in[16];
    const float* l0b  = (const float*)d_in[17];
    const float* l1w  = (const float*)d_in[18];
    const float* l1b  = (const float*)d_in[19];
    const float* l2w  = (const float*)d_in[20];
    const float* l2b  = (const float*)d_in[21];
    const float* offw = (const float*)d_in[22];
    const float* offb = (const float*)d_in[23];
    const float* aww  = (const float*)d_in[24];
    const float* awb  = (const float*)d_in[25];
    const float* valw = (const float*)d_in[26];
    const float* valb = (const float*)d_in[27];
    const float* ojw  = (const float*)d_in[28];
    const float* ojb  = (const float*)d_in[29];

    float* ws     = (float*)d_ws;
    float* qkv    = ws;              // 98304
    float* x1     = ws + 98304;      // 32768
    float* feat   = ws + 131072;     // 245760
    float* nrow   = ws + 376832;     // 98304
    float* offatr = ws + 475136;     // 147456
    float* ca     = ws + 622592;     // 98304
    float* refxy  = ws + 720896;     // 768
    int*   lxly   = (int*)(ws + 721664); // 3072 ints
    float* opwT   = ws + 724736;     // 65536
    float* ojwT   = ws + 790272;     // 65536
    float* valwT  = ws + 855808;     // 65536
    float* l1wT   = ws + 921344;     // 262144
    float* l2wT   = ws + 1183488;    // 262144

    k_prep<<<896, 256, 0, stream>>>(tgt, qpos, ipw, ipb, opw, ojw, valw, l1w, l2w,
                                    qkv, opwT, ojwT, valwT, l1wT, l2wT);
    k_edge<<<128, 256, 0, stream>>>(qkv, tgt, qpos, opwT, opb, n2w, n2b, ec,
                                    x1, feat, refxy, lxly);
    k_gemm<640, 0, 0, 0><<<192, 256, 0, stream>>>(feat, nullptr, l0w, nullptr, l0b, nullptr, nrow, 256, 32);
    k_gemm<256, 0, 0, 1><<<288, 256, 0, stream>>>(nrow, nullptr, offw, aww, offb, awb, offatr, 384, 48);
    k_sample<<<3072, 256, 0, stream>>>(offatr, refxy, vr, lxly, src, mask, valwT, valb, ca);
    k_tail<<<128, 256, 0, stream>>>(ca, x1, ojwT, ojb, n1w, n1b, l1wT, l1b, l2wT, l2b, n3w, n3b, (float*)d_out);
}

// Round 7
// 353.745 us; speedup vs baseline: 3.2076x; 1.0830x over previous
//
#include <hip/hip_runtime.h>
#include <math.h>

// All inputs/outputs fp32 (verified R2).
// R7: 4-stage pipeline (prep -> edge -> sample -> tail), 1024-thread blocks
// for the per-edge kernels. R6 showed k_tail at 70us with occupancy 5.4%:
// 128 blocks x 4 waves = 1 wave/SIMD -> latency-bound despite coalescing.
// Fix: 16 waves/block + split every matvec output x K-chunk, and merge the
// nq/off gemm stages into k_edge (fewer serial stage latencies).

// sum over the first 256 lanes' v; callable from 1024-thread blocks
__device__ __forceinline__ float block_sum256w(float v, float* red) {
    int t = threadIdx.x;
    if (t < 256) red[t] = v;
    __syncthreads();
    for (int st = 128; st > 0; st >>= 1) {
        if (t < st) red[t] += red[t + st];
        __syncthreads();
    }
    float r = red[0]; __syncthreads();
    return r;
}

// ---- tiled GEMM unit (R4-verified): 64 rows x 8 outputs, W rows scalar-cached ----
// MI=1 qkv (o<512 adds IN2; stride 256); MO=2 scale o<256 by 32^-0.5
template <int K, int MI, int MO>
__device__ void gemm_unit(const float* __restrict__ IN, const float* __restrict__ IN2,
                          const float* __restrict__ W, const float* __restrict__ B,
                          float* __restrict__ OUT, int O, int OG, int u, float* smem) {
    constexpr int KC = 128;
    constexpr int LDT = KC + 4;
    float* tile = smem;
    int og = u % OG, rg = u / OG;
    int o0 = og * 8, r0 = rg * 64;
    int t = threadIdx.x;
    int r = t & 63;
    int ol = __builtin_amdgcn_readfirstlane(t >> 6);
    int oa = o0 + ol, ob = o0 + 4 + ol;
    const float* Wa = W + (size_t)oa * K;
    const float* Wb = W + (size_t)ob * K;
    float Ba = B[oa], Bb = B[ob];
    float acca = 0.f, accb = 0.f;
    for (int c = 0; c < K / KC; c++) {
        for (int idx = t; idx < 64 * KC; idx += 256) {
            int rr = idx >> 7, ii = idx & (KC - 1);
            int row = r0 + rr, col = c * KC + ii;
            float v;
            if (MI == 0) {
                v = IN[(size_t)row * K + col];
            } else {
                float tv = IN[row * 256 + col];
                v = (o0 < 512) ? tv + IN2[row * 256 + col] : tv;
            }
            tile[rr * LDT + ii] = v;
        }
        __syncthreads();
        const float4* wa4 = (const float4*)(Wa + c * KC);
        const float4* wb4 = (const float4*)(Wb + c * KC);
        const float4* trow = (const float4*)(tile + r * LDT);
        #pragma unroll
        for (int i4 = 0; i4 < KC / 4; i4++) {
            float4 x4 = trow[i4];
            float4 a4 = wa4[i4];
            float4 b4 = wb4[i4];
            acca += x4.x * a4.x; acca += x4.y * a4.y;
            acca += x4.z * a4.z; acca += x4.w * a4.w;
            accb += x4.x * b4.x; accb += x4.y * b4.y;
            accb += x4.z * b4.z; accb += x4.w * b4.w;
        }
        __syncthreads();
    }
    acca += Ba; accb += Bb;
    if (MO == 2) {
        if (oa < 256) acca *= 0.17677669529663687f;
        if (ob < 256) accb *= 0.17677669529663687f;
    }
    OUT[(size_t)(r0 + r) * O + oa] = acca;
    OUT[(size_t)(r0 + r) * O + ob] = accb;
}

// ---- 32x32 transpose unit: out (C,R) = in (R,C)^T ----
__device__ void transpose_unit(const float* __restrict__ in, float* __restrict__ out,
                               int R, int C, int u, float* smem) {
    int TC = C >> 5;
    int tc = u % TC, tr = u / TC;
    int t = threadIdx.x;
    int lr = t >> 5, lc = t & 31;
    #pragma unroll
    for (int rr = 0; rr < 32; rr += 8) {
        smem[(rr + lr) * 33 + lc] = in[(size_t)(tr * 32 + rr + lr) * C + tc * 32 + lc];
    }
    __syncthreads();
    #pragma unroll
    for (int rr = 0; rr < 32; rr += 8) {
        out[(size_t)(tc * 32 + rr + lr) * R + tr * 32 + lc] = smem[lc * 33 + rr + lr];
    }
    __syncthreads();
}

// ---------------- S1: qkv gemm + all weight transposes ----------------
// grid 1152, block 256
__global__ __launch_bounds__(256) void k_prep(const float* __restrict__ tgt,
                                              const float* __restrict__ qpos,
                                              const float* __restrict__ ipw,
                                              const float* __restrict__ ipb,
                                              const float* __restrict__ opw,
                                              const float* __restrict__ ojw,
                                              const float* __restrict__ valw,
                                              const float* __restrict__ l1w,
                                              const float* __restrict__ l2w,
                                              const float* __restrict__ l0w,
                                              const float* __restrict__ offw,
                                              const float* __restrict__ aww,
                                              float* __restrict__ qkv,
                                              float* __restrict__ opwT,
                                              float* __restrict__ ojwT,
                                              float* __restrict__ valwT,
                                              float* __restrict__ l1wT,
                                              float* __restrict__ l2wT,
                                              float* __restrict__ l0wT,
                                              float* __restrict__ offwT,
                                              float* __restrict__ awwT) {
    __shared__ __align__(16) float smem[8448];
    int u = blockIdx.x;
    if (u < 192)       gemm_unit<256, 1, 2>(tgt, qpos, ipw, ipb, qkv, 768, 96, u, smem);
    else if (u < 256)  transpose_unit(opw, opwT, 256, 256, u - 192, smem);
    else if (u < 320)  transpose_unit(ojw, ojwT, 256, 256, u - 256, smem);
    else if (u < 384)  transpose_unit(valw, valwT, 256, 256, u - 320, smem);
    else if (u < 640)  transpose_unit(l1w, l1wT, 1024, 256, u - 384, smem);
    else if (u < 896)  transpose_unit(l2w, l2wT, 256, 1024, u - 640, smem);
    else if (u < 1056) transpose_unit(l0w, l0wT, 256, 640, u - 896, smem);
    else if (u < 1120) transpose_unit(offw, offwT, 256, 256, u - 1056, smem);
    else               transpose_unit(aww, awwT, 128, 256, u - 1120, smem);
}

// ---- geometry for edge e, point j: returns pxs/pys triples + box mins ----
__device__ __forceinline__ void edge_geom(const float* __restrict__ ec, int e, int j,
                                          float* pxs, float* pys,
                                          float& fminx, float& fminy,
                                          float& cxf, float& cyf) {
    float ax = ec[e * 4 + 0], ay = ec[e * 4 + 1];
    float bx = ec[e * 4 + 2], by = ec[e * 4 + 3];
    float dx = bx - ax, dy = by - ay;
    float tj = 0.5f * (float)j;
    float ptx = __fadd_rn(ax, __fmul_rn(tj, dx));
    float pty = __fadd_rn(ay, __fmul_rn(tj, dy));
    cxf = floorf(ptx); cyf = floorf(pty);
    int minx = max((int)cxf - 128, 0); if (minx + 256 > 2048) minx = 2048 - 256;
    int miny = max((int)cyf - 128, 0); if (miny + 256 > 2048) miny = 2048 - 256;
    fminx = (float)minx; fminy = (float)miny;
    float tlx, thx, tly, thy;
    if (dx == 0.f) { tlx = 0.f; thx = 1.f; }
    else { float u1 = (fminx - ax) / dx, u2 = (fminx + 256.f - ax) / dx; tlx = fminf(u1, u2); thx = fmaxf(u1, u2); }
    if (dy == 0.f) { tly = 0.f; thy = 1.f; }
    else { float u1 = (fminy - ay) / dy, u2 = (fminy + 256.f - ay) / dy; tly = fminf(u1, u2); thy = fmaxf(u1, u2); }
    float t0 = fmaxf(fmaxf(tlx, tly), 0.f);
    float t1 = fmaxf(fminf(fminf(thx, thy), 1.f), t0);
    pxs[0] = __fadd_rn(ax, __fmul_rn(t0, dx)); pys[0] = __fadd_rn(ay, __fmul_rn(t0, dy));
    pxs[1] = __fadd_rn(ax, __fmul_rn(t1, dx)); pys[1] = __fadd_rn(ay, __fmul_rn(t1, dy));
    pxs[2] = cxf; pys[2] = cyf;
}

// ---------------- S2: attn + oproj + norm2 + 3x(pe + nq + off/attw) ----------------
// grid 128 (per edge), block 1024
__global__ __launch_bounds__(1024) void k_edge(const float* __restrict__ qkv,
                                               const float* __restrict__ tgt,
                                               const float* __restrict__ qpos,
                                               const float* __restrict__ opwT,
                                               const float* __restrict__ opb,
                                               const float* __restrict__ n2w,
                                               const float* __restrict__ n2b,
                                               const float* __restrict__ ec,
                                               const float* __restrict__ l0wT,
                                               const float* __restrict__ l0b,
                                               const float* __restrict__ offwT,
                                               const float* __restrict__ offb,
                                               const float* __restrict__ awwT,
                                               const float* __restrict__ awb,
                                               float* __restrict__ x1,
                                               float* __restrict__ offatr,
                                               float* __restrict__ refxy,
                                               int* __restrict__ lxly) {
    int e = blockIdx.x, t = threadIdx.x;
    __shared__ float sq[256], sS[1024], smax[8], ssum[8], srow[256];
    __shared__ float part[1024], red[256], xq[256];
    __shared__ float pe3[1152], nrow3[768];
    // ---- attention scores: one per thread ----
    if (t < 256) sq[t] = qkv[e * 768 + t];
    __syncthreads();
    {
        int h = t >> 7, f = t & 127;
        const float* kf = qkv + f * 768 + 256 + h * 32;
        const float* qh = sq + h * 32;
        float s = 0.f;
        #pragma unroll 8
        for (int d = 0; d < 32; d++) s += qh[d] * kf[d];
        sS[t] = s;
    }
    __syncthreads();
    if (t < 8) {
        float m = -1e30f;
        for (int f = 0; f < 128; f++) m = fmaxf(m, sS[t * 128 + f]);
        smax[t] = m;
    }
    __syncthreads();
    sS[t] = __expf(sS[t] - smax[t >> 7]);
    __syncthreads();
    if (t < 8) {
        float s = 0.f;
        for (int f = 0; f < 128; f++) s += sS[t * 128 + f];
        ssum[t] = 1.f / s;
    }
    __syncthreads();
    // ---- PV: 256 outputs x 4 chunks of 32 keys ----
    {
        int o = t & 255, c = t >> 8, h = o >> 5, d = o & 31;
        float acc = 0.f;
        #pragma unroll 8
        for (int f = c * 32; f < c * 32 + 32; f++)
            acc += sS[h * 128 + f] * qkv[f * 768 + 512 + h * 32 + d];
        part[t] = acc;
    }
    __syncthreads();
    if (t < 256) srow[t] = (part[t] + part[256 + t] + part[512 + t] + part[768 + t]) * ssum[t >> 5];
    __syncthreads();
    // ---- oproj: 256 outputs x 4 chunks of 64 ----
    {
        int o = t & 255, c = t >> 8;
        float acc = 0.f;
        #pragma unroll 8
        for (int i = c * 64; i < c * 64 + 64; i++) acc += srow[i] * opwT[(size_t)i * 256 + o];
        part[t] = acc;
    }
    __syncthreads();
    // ---- norm2 (first 256 lanes) ----
    {
        float acc = 0.f;
        if (t < 256) acc = part[t] + part[256 + t] + part[512 + t] + part[768 + t] + opb[t] + tgt[e * 256 + t];
        float mean = block_sum256w(acc, red) * (1.f / 256.f);
        float d0 = acc - mean;
        float var = block_sum256w((t < 256) ? d0 * d0 : 0.f, red) * (1.f / 256.f);
        if (t < 256) {
            float xln = d0 * rsqrtf(var + 1e-5f) * n2w[t] + n2b[t];
            x1[e * 256 + t] = xln;
            xq[t] = xln + qpos[e * 256 + t];
        }
    }
    // ---- pos-encode for 3 points: 1152 elements ----
    #pragma unroll
    for (int rep = 0; rep < 2; rep++) {
        int idx = rep * 1024 + t;
        if (idx < 1152) {
            int j = idx / 384, w = idx - j * 384;
            float pxs[3], pys[3], fmx, fmy, cxf, cyf;
            edge_geom(ec, e, j, pxs, pys, fmx, fmy, cxf, cyf);
            int jj = w >> 7, tt = w & 127, i = tt & 63, kk = i >> 1;
            float invd = __expf(-(float)kk * (9.210340371976184f / 32.f));  // 10000^(-kk/32)
            float vv = (tt < 64) ? pys[jj] : pxs[jj];
            float pp = vv * invd;
            pe3[idx] = (i & 1) ? __cosf(pp) : __sinf(pp);
        }
    }
    if (t < 3) {
        int j = t, n = 3 * e + j;
        float pxs[3], pys[3], fmx, fmy, cxf, cyf;
        edge_geom(ec, e, j, pxs, pys, fmx, fmy, cxf, cyf);
        refxy[n * 2 + 0] = (cxf - fmx) * (1.f / 256.f);
        refxy[n * 2 + 1] = (cyf - fmy) * (1.f / 256.f);
        lxly[n * 8 + 0] = (int)rintf(fmx * 0.125f);
        lxly[n * 8 + 1] = (int)rintf(fmx * 0.0625f);
        lxly[n * 8 + 2] = (int)rintf(fmx * 0.03125f);
        lxly[n * 8 + 3] = (int)rintf(fmx * 0.015625f);
        lxly[n * 8 + 4] = (int)rintf(fmy * 0.125f);
        lxly[n * 8 + 5] = (int)rintf(fmy * 0.0625f);
        lxly[n * 8 + 6] = (int)rintf(fmy * 0.03125f);
        lxly[n * 8 + 7] = (int)rintf(fmy * 0.015625f);
    }
    __syncthreads();
    // ---- nq for 3 points: 768 threads, full K=640 dot each ----
    if (t < 768) {
        int o = t & 255, j = t >> 8;
        float acc = l0b[o];
        #pragma unroll 4
        for (int i = 0; i < 256; i++) acc += xq[i] * l0wT[(size_t)i * 256 + o];
        const float* pj = pe3 + j * 384;
        #pragma unroll 4
        for (int i = 0; i < 384; i++) acc += pj[i] * l0wT[(size_t)(256 + i) * 256 + o];
        nrow3[j * 256 + o] = acc;
    }
    __syncthreads();
    // ---- off (768 outputs) + attw (384 outputs) ----
    if (t < 768) {
        int o = t & 255, j = t >> 8;
        const float* nr = nrow3 + j * 256;
        float acc = offb[o];
        #pragma unroll 8
        for (int i = 0; i < 256; i++) acc += nr[i] * offwT[(size_t)i * 256 + o];
        offatr[(size_t)(3 * e + j) * 384 + o] = acc;
    }
    if (t < 384) {
        int o = t & 127, j = t >> 7;
        const float* nr = nrow3 + j * 256;
        float acc = awb[o];
        #pragma unroll 8
        for (int i = 0; i < 256; i++) acc += nr[i] * awwT[(size_t)i * 128 + o];
        offatr[(size_t)(3 * e + j) * 384 + 256 + o] = acc;
    }
}

// ---------------- S3: deformable sampling (linearity-fused, valwT) ----------------
// grid N*H=3072, block 256
__global__ __launch_bounds__(256) void k_sample(const float* __restrict__ offatr,
                                                const float* __restrict__ refxy,
                                                const float* __restrict__ vr,
                                                const int* __restrict__ lxly,
                                                const float* __restrict__ src,
                                                const unsigned char* __restrict__ mask,
                                                const float* __restrict__ valwT,
                                                const float* __restrict__ valb,
                                                float* __restrict__ ca) {
    int n = blockIdx.x >> 3, h = blockIdx.x & 7, t = threadIdx.x;
    __shared__ float cw[64];
    __shared__ int cg[64];
    __shared__ float agg[256];
    __shared__ float sl[16], sred[2];
    __shared__ float pagg[32 * 8];
    if (t < 16) sl[t] = offatr[n * 384 + 256 + h * 16 + t];
    __syncthreads();
    if (t == 0) {
        float m = -1e30f;
        for (int i = 0; i < 16; i++) m = fmaxf(m, sl[i]);
        float s = 0.f;
        for (int i = 0; i < 16; i++) s += __expf(sl[i] - m);
        sred[0] = m; sred[1] = 1.f / s;
    }
    __syncthreads();
    if (t < 64) {
        int l = t >> 4, pp = (t >> 2) & 3, tap = t & 3;
        int s = 32 >> l;
        int wl = 256 >> l;
        const int img_starts[4] = {0, 65536, 81920, 86016};
        float a = __expf(sl[l * 4 + pp] - sred[0]) * sred[1];
        float slv = (float)s;
        float gx = refxy[n * 2 + 0] * vr[l * 2 + 0] + offatr[n * 384 + h * 32 + l * 8 + pp * 2 + 0] / slv;
        float gy = refxy[n * 2 + 1] * vr[l * 2 + 1] + offatr[n * 384 + h * 32 + l * 8 + pp * 2 + 1] / slv;
        float px = gx * slv - 0.5f, py = gy * slv - 0.5f;
        float x0 = floorf(px), y0 = floorf(py);
        float fx = px - x0, fy = py - y0;
        int xi = (int)x0 + (tap & 1), yi = (int)y0 + (tap >> 1);
        float wt = ((tap & 1) ? fx : (1.f - fx)) * ((tap >> 1) ? fy : (1.f - fy));
        int g = -1;
        if (xi >= 0 && xi < s && yi >= 0 && yi < s) {
            int col = lxly[n * 8 + l] + xi;
            int row = lxly[n * 8 + 4 + l] + yi;
            g = img_starts[l] + row * wl + col;
            if (mask[g]) g = -1;  // masked rows zeroed (incl. bias)
        }
        cw[t] = a * wt;
        cg[t] = g;
    }
    __syncthreads();
    float acc = 0.f, csum = 0.f;
    for (int tp = 0; tp < 64; tp++) {
        int g = cg[tp];
        if (g >= 0) {
            acc += cw[tp] * src[(size_t)g * 256 + t];
            csum += cw[tp];
        }
    }
    agg[t] = acc;
    __syncthreads();
    {
        int o = t & 31, qtr = t >> 5;
        float pv = 0.f;
        #pragma unroll
        for (int i = 0; i < 32; i++) {
            int ii = qtr * 32 + i;
            pv += agg[ii] * valwT[(size_t)ii * 256 + h * 32 + o];
        }
        pagg[o * 8 + qtr] = pv;
    }
    __syncthreads();
    if (t < 32) {
        float o = 0.f;
        for (int qtr = 0; qtr < 8; qtr++) o += pagg[t * 8 + qtr];
        ca[n * 256 + h * 32 + t] = o + csum * valb[h * 32 + t];
    }
}

// ---------------- S4: pool + oproj + norm1 + ffn1 + ffn2 + norm3 ----------------
// grid 128 (per edge), block 1024
__global__ __launch_bounds__(1024) void k_tail(const float* __restrict__ ca,
                                               const float* __restrict__ x1,
                                               const float* __restrict__ ojwT,
                                               const float* __restrict__ ojb,
                                               const float* __restrict__ n1w,
                                               const float* __restrict__ n1b,
                                               const float* __restrict__ l1wT,
                                               const float* __restrict__ l1b,
                                               const float* __restrict__ l2wT,
                                               const float* __restrict__ l2b,
                                               const float* __restrict__ n3w,
                                               const float* __restrict__ n3b,
                                               float* __restrict__ out) {
    int e = blockIdx.x, t = threadIdx.x;
    __shared__ float row[256], red[256], x2s[256], h1s[1024], part[1024];
    if (t < 256)
        row[t] = (ca[(3 * e) * 256 + t] + ca[(3 * e + 1) * 256 + t] + ca[(3 * e + 2) * 256 + t]) * (1.f / 3.f);
    __syncthreads();
    // oproj: 256 outputs x 4 chunks of 64
    {
        int o = t & 255, c = t >> 8;
        float acc = 0.f;
        #pragma unroll 8
        for (int i = c * 64; i < c * 64 + 64; i++) acc += row[i] * ojwT[(size_t)i * 256 + o];
        part[t] = acc;
    }
    __syncthreads();
    // norm1
    {
        float acc = 0.f;
        if (t < 256) acc = part[t] + part[256 + t] + part[512 + t] + part[768 + t] + ojb[t] + x1[e * 256 + t];
        float mean = block_sum256w(acc, red) * (1.f / 256.f);
        float d0 = acc - mean;
        float var = block_sum256w((t < 256) ? d0 * d0 : 0.f, red) * (1.f / 256.f);
        if (t < 256) x2s[t] = d0 * rsqrtf(var + 1e-5f) * n1w[t] + n1b[t];
    }
    __syncthreads();
    // ffn1: one output per thread
    {
        float acc = l1b[t];
        #pragma unroll 8
        for (int i = 0; i < 256; i++) acc += x2s[i] * l1wT[(size_t)i * 1024 + t];
        h1s[t] = fmaxf(acc, 0.f);
    }
    __syncthreads();
    // ffn2: 256 outputs x 4 chunks of 256
    {
        int o = t & 255, c = t >> 8;
        float acc = 0.f;
        #pragma unroll 8
        for (int i = c * 256; i < c * 256 + 256; i++) acc += h1s[i] * l2wT[(size_t)i * 256 + o];
        part[t] = acc;
    }
    __syncthreads();
    // norm3 -> out
    {
        float acc = 0.f;
        if (t < 256) acc = part[t] + part[256 + t] + part[512 + t] + part[768 + t] + l2b[t] + x2s[t];
        float mean = block_sum256w(acc, red) * (1.f / 256.f);
        float d0 = acc - mean;
        float var = block_sum256w((t < 256) ? d0 * d0 : 0.f, red) * (1.f / 256.f);
        if (t < 256) out[e * 256 + t] = d0 * rsqrtf(var + 1e-5f) * n3w[t] + n3b[t];
    }
}

extern "C" void kernel_launch(void* const* d_in, const int* in_sizes, int n_in,
                              void* d_out, int out_size, void* d_ws, size_t ws_size,
                              hipStream_t stream) {
    (void)in_sizes; (void)n_in; (void)out_size; (void)ws_size;
    const float* tgt  = (const float*)d_in[0];
    const float* qpos = (const float*)d_in[1];
    const float* ec   = (const float*)d_in[2];
    const float* src  = (const float*)d_in[3];
    const unsigned char* mask = (const unsigned char*)d_in[4];
    const float* vr   = (const float*)d_in[5];
    const float* ipw  = (const float*)d_in[6];
    const float* ipb  = (const float*)d_in[7];
    const float* opw  = (const float*)d_in[8];
    const float* opb  = (const float*)d_in[9];
    const float* n1w  = (const float*)d_in[10];
    const float* n1b  = (const float*)d_in[11];
    const float* n2w  = (const float*)d_in[12];
    const float* n2b  = (const float*)d_in[13];
    const float* n3w  = (const float*)d_in[14];
    const float* n3b  = (const float*)d_in[15];
    const float* l0w  = (const float*)d_in[16];
    const float* l0b  = (const float*)d_in[17];
    const float* l1w  = (const float*)d_in[18];
    const float* l1b  = (const float*)d_in[19];
    const float* l2w  = (const float*)d_in[20];
    const float* l2b  = (const float*)d_in[21];
    const float* offw = (const float*)d_in[22];
    const float* offb = (const float*)d_in[23];
    const float* aww  = (const float*)d_in[24];
    const float* awb  = (const float*)d_in[25];
    const float* valw = (const float*)d_in[26];
    const float* valb = (const float*)d_in[27];
    const float* ojw  = (const float*)d_in[28];
    const float* ojb  = (const float*)d_in[29];

    float* ws     = (float*)d_ws;
    float* qkv    = ws;               // 98304
    float* x1     = ws + 98304;       // 32768
    float* offatr = ws + 131072;      // 147456
    float* ca     = ws + 278528;      // 98304
    float* refxy  = ws + 376832;      // 768
    int*   lxly   = (int*)(ws + 377600); // 3072 ints
    float* opwT   = ws + 380672;      // 65536
    float* ojwT   = ws + 446208;      // 65536
    float* valwT  = ws + 511744;      // 65536
    float* l1wT   = ws + 577280;      // 262144
    float* l2wT   = ws + 839424;      // 262144
    float* l0wT   = ws + 1101568;     // 163840
    float* offwT  = ws + 1265408;     // 65536
    float* awwT   = ws + 1330944;     // 32768

    k_prep<<<1152, 256, 0, stream>>>(tgt, qpos, ipw, ipb, opw, ojw, valw, l1w, l2w,
                                     l0w, offw, aww,
                                     qkv, opwT, ojwT, valwT, l1wT, l2wT, l0wT, offwT, awwT);
    k_edge<<<128, 1024, 0, stream>>>(qkv, tgt, qpos, opwT, opb, n2w, n2b, ec,
                                     l0wT, l0b, offwT, offb, awwT, awb,
                                     x1, offatr, refxy, lxly);
    k_sample<<<3072, 256, 0, stream>>>(offatr, refxy, vr, lxly, src, mask, valwT, valb, ca);
    k_tail<<<128, 1024, 0, stream>>>(ca, x1, ojwT, ojb, n1w, n1b, l1wT, l1b, l2wT, l2b, n3w, n3b, (float*)d_out);
}

// Round 8
// 324.065 us; speedup vs baseline: 3.5014x; 1.0916x over previous
//
#include <hip/hip_runtime.h>
#include <math.h>

// All inputs/outputs fp32 (verified R2).
// R8: k_edge's fused matvecs (nq K=640, off/attw K=256) converted from
// per-thread serial global-load chains (R7: 82us, VALUBusy 6.4%) to
// cooperatively LDS-staged weight tiles: 1024 threads stage 32xO tile via
// independent float4 loads, compute from LDS. off+attw pre-concatenated
// into oawT(256,384) by k_prep. Shared pool phase-aliased to 57.8KB.

__device__ __forceinline__ float block_sum256w(float v, float* red) {
    int t = threadIdx.x;
    if (t < 256) red[t] = v;
    __syncthreads();
    for (int st = 128; st > 0; st >>= 1) {
        if (t < st) red[t] += red[t + st];
        __syncthreads();
    }
    float r = red[0]; __syncthreads();
    return r;
}

// ---- tiled GEMM unit (R4-verified): 64 rows x 8 outputs, W rows scalar-cached ----
// MI=1 qkv (o<512 adds IN2; stride 256); MO=2 scale o<256 by 32^-0.5
template <int K, int MI, int MO>
__device__ void gemm_unit(const float* __restrict__ IN, const float* __restrict__ IN2,
                          const float* __restrict__ W, const float* __restrict__ B,
                          float* __restrict__ OUT, int O, int OG, int u, float* smem) {
    constexpr int KC = 128;
    constexpr int LDT = KC + 4;
    float* tile = smem;
    int og = u % OG, rg = u / OG;
    int o0 = og * 8, r0 = rg * 64;
    int t = threadIdx.x;
    int r = t & 63;
    int ol = __builtin_amdgcn_readfirstlane(t >> 6);
    int oa = o0 + ol, ob = o0 + 4 + ol;
    const float* Wa = W + (size_t)oa * K;
    const float* Wb = W + (size_t)ob * K;
    float Ba = B[oa], Bb = B[ob];
    float acca = 0.f, accb = 0.f;
    for (int c = 0; c < K / KC; c++) {
        for (int idx = t; idx < 64 * KC; idx += 256) {
            int rr = idx >> 7, ii = idx & (KC - 1);
            int row = r0 + rr, col = c * KC + ii;
            float v;
            if (MI == 0) {
                v = IN[(size_t)row * K + col];
            } else {
                float tv = IN[row * 256 + col];
                v = (o0 < 512) ? tv + IN2[row * 256 + col] : tv;
            }
            tile[rr * LDT + ii] = v;
        }
        __syncthreads();
        const float4* wa4 = (const float4*)(Wa + c * KC);
        const float4* wb4 = (const float4*)(Wb + c * KC);
        const float4* trow = (const float4*)(tile + r * LDT);
        #pragma unroll
        for (int i4 = 0; i4 < KC / 4; i4++) {
            float4 x4 = trow[i4];
            float4 a4 = wa4[i4];
            float4 b4 = wb4[i4];
            acca += x4.x * a4.x; acca += x4.y * a4.y;
            acca += x4.z * a4.z; acca += x4.w * a4.w;
            accb += x4.x * b4.x; accb += x4.y * b4.y;
            accb += x4.z * b4.z; accb += x4.w * b4.w;
        }
        __syncthreads();
    }
    acca += Ba; accb += Bb;
    if (MO == 2) {
        if (oa < 256) acca *= 0.17677669529663687f;
        if (ob < 256) accb *= 0.17677669529663687f;
    }
    OUT[(size_t)(r0 + r) * O + oa] = acca;
    OUT[(size_t)(r0 + r) * O + ob] = accb;
}

// ---- 32x32 transpose unit: in (R,C); writes out[(c)*S + F + r] ----
__device__ void transpose_unit(const float* __restrict__ in, float* __restrict__ out,
                               int R, int C, int S, int F, int u, float* smem) {
    int TC = C >> 5;
    int tc = u % TC, tr = u / TC;
    int t = threadIdx.x;
    int lr = t >> 5, lc = t & 31;
    #pragma unroll
    for (int rr = 0; rr < 32; rr += 8) {
        smem[(rr + lr) * 33 + lc] = in[(size_t)(tr * 32 + rr + lr) * C + tc * 32 + lc];
    }
    __syncthreads();
    #pragma unroll
    for (int rr = 0; rr < 32; rr += 8) {
        out[(size_t)(tc * 32 + rr + lr) * S + F + tr * 32 + lc] = smem[lc * 33 + rr + lr];
    }
    __syncthreads();
}

// ---------------- S1: qkv gemm + all weight transposes ----------------
// grid 1152, block 256
__global__ __launch_bounds__(256) void k_prep(const float* __restrict__ tgt,
                                              const float* __restrict__ qpos,
                                              const float* __restrict__ ipw,
                                              const float* __restrict__ ipb,
                                              const float* __restrict__ opw,
                                              const float* __restrict__ ojw,
                                              const float* __restrict__ valw,
                                              const float* __restrict__ l1w,
                                              const float* __restrict__ l2w,
                                              const float* __restrict__ l0w,
                                              const float* __restrict__ offw,
                                              const float* __restrict__ aww,
                                              float* __restrict__ qkv,
                                              float* __restrict__ opwT,
                                              float* __restrict__ ojwT,
                                              float* __restrict__ valwT,
                                              float* __restrict__ l1wT,
                                              float* __restrict__ l2wT,
                                              float* __restrict__ l0wT,
                                              float* __restrict__ oawT) {
    __shared__ __align__(16) float smem[8448];
    int u = blockIdx.x;
    if (u < 192)       gemm_unit<256, 1, 2>(tgt, qpos, ipw, ipb, qkv, 768, 96, u, smem);
    else if (u < 256)  transpose_unit(opw, opwT, 256, 256, 256, 0, u - 192, smem);
    else if (u < 320)  transpose_unit(ojw, ojwT, 256, 256, 256, 0, u - 256, smem);
    else if (u < 384)  transpose_unit(valw, valwT, 256, 256, 256, 0, u - 320, smem);
    else if (u < 640)  transpose_unit(l1w, l1wT, 1024, 256, 1024, 0, u - 384, smem);
    else if (u < 896)  transpose_unit(l2w, l2wT, 256, 1024, 256, 0, u - 640, smem);
    else if (u < 1056) transpose_unit(l0w, l0wT, 256, 640, 256, 0, u - 896, smem);
    else if (u < 1120) transpose_unit(offw, oawT, 256, 256, 384, 0, u - 1056, smem);
    else               transpose_unit(aww, oawT, 128, 256, 384, 256, u - 1120, smem);
}

// ---- geometry for edge e, point j ----
__device__ __forceinline__ void edge_geom(const float* __restrict__ ec, int e, int j,
                                          float* pxs, float* pys,
                                          float& fminx, float& fminy,
                                          float& cxf, float& cyf) {
    float ax = ec[e * 4 + 0], ay = ec[e * 4 + 1];
    float bx = ec[e * 4 + 2], by = ec[e * 4 + 3];
    float dx = bx - ax, dy = by - ay;
    float tj = 0.5f * (float)j;
    float ptx = __fadd_rn(ax, __fmul_rn(tj, dx));
    float pty = __fadd_rn(ay, __fmul_rn(tj, dy));
    cxf = floorf(ptx); cyf = floorf(pty);
    int minx = max((int)cxf - 128, 0); if (minx + 256 > 2048) minx = 2048 - 256;
    int miny = max((int)cyf - 128, 0); if (miny + 256 > 2048) miny = 2048 - 256;
    fminx = (float)minx; fminy = (float)miny;
    float tlx, thx, tly, thy;
    if (dx == 0.f) { tlx = 0.f; thx = 1.f; }
    else { float u1 = (fminx - ax) / dx, u2 = (fminx + 256.f - ax) / dx; tlx = fminf(u1, u2); thx = fmaxf(u1, u2); }
    if (dy == 0.f) { tly = 0.f; thy = 1.f; }
    else { float u1 = (fminy - ay) / dy, u2 = (fminy + 256.f - ay) / dy; tly = fminf(u1, u2); thy = fmaxf(u1, u2); }
    float t0 = fmaxf(fmaxf(tlx, tly), 0.f);
    float t1 = fmaxf(fminf(fminf(thx, thy), 1.f), t0);
    pxs[0] = __fadd_rn(ax, __fmul_rn(t0, dx)); pys[0] = __fadd_rn(ay, __fmul_rn(t0, dy));
    pxs[1] = __fadd_rn(ax, __fmul_rn(t1, dx)); pys[1] = __fadd_rn(ay, __fmul_rn(t1, dy));
    pxs[2] = cxf; pys[2] = cyf;
}

// ---------------- S2: attn + oproj + norm2 + 3x(pe + nq + off/attw) ----------------
// grid 128 (per edge), block 1024. Shared pool phase-aliased:
//   A (attn/oproj/norm2): sq@0(256) sS@256(1024) smax@1280(8) ssum@1288(8)
//                         srow@1296(256) part@1552(1024) red@2576(256)
//   persists:             xq@14208(256)
//   B (pe/nq/off):        pe3@0(1152) nrow3@1152(768) wtile@1920(12288)
__global__ __launch_bounds__(1024) void k_edge(const float* __restrict__ qkv,
                                               const float* __restrict__ tgt,
                                               const float* __restrict__ qpos,
                                               const float* __restrict__ opwT,
                                               const float* __restrict__ opb,
                                               const float* __restrict__ n2w,
                                               const float* __restrict__ n2b,
                                               const float* __restrict__ ec,
                                               const float* __restrict__ l0wT,
                                               const float* __restrict__ l0b,
                                               const float* __restrict__ oawT,
                                               const float* __restrict__ offb,
                                               const float* __restrict__ awb,
                                               float* __restrict__ x1,
                                               float* __restrict__ offatr,
                                               float* __restrict__ refxy,
                                               int* __restrict__ lxly) {
    int e = blockIdx.x, t = threadIdx.x;
    __shared__ __align__(16) float SH[14464];  // 57856 B
    float* sq   = SH;
    float* sS   = SH + 256;
    float* smax = SH + 1280;
    float* ssum = SH + 1288;
    float* srow = SH + 1296;
    float* part = SH + 1552;
    float* red  = SH + 2576;
    float* xq   = SH + 14208;
    float* pe3  = SH;          // phase B
    float* nrow3 = SH + 1152;  // phase B
    float* wtile = SH + 1920;  // phase B
    // ---- attention scores ----
    if (t < 256) sq[t] = qkv[e * 768 + t];
    __syncthreads();
    {
        int h = t >> 7, f = t & 127;
        const float* kf = qkv + f * 768 + 256 + h * 32;
        const float* qh = sq + h * 32;
        float s = 0.f;
        #pragma unroll 8
        for (int d = 0; d < 32; d++) s += qh[d] * kf[d];
        sS[t] = s;
    }
    __syncthreads();
    if (t < 8) {
        float m = -1e30f;
        for (int f = 0; f < 128; f++) m = fmaxf(m, sS[t * 128 + f]);
        smax[t] = m;
    }
    __syncthreads();
    sS[t] = __expf(sS[t] - smax[t >> 7]);
    __syncthreads();
    if (t < 8) {
        float s = 0.f;
        for (int f = 0; f < 128; f++) s += sS[t * 128 + f];
        ssum[t] = 1.f / s;
    }
    __syncthreads();
    // ---- PV: 256 outputs x 4 chunks of 32 keys ----
    {
        int o = t & 255, c = t >> 8, h = o >> 5, d = o & 31;
        float acc = 0.f;
        #pragma unroll 8
        for (int f = c * 32; f < c * 32 + 32; f++)
            acc += sS[h * 128 + f] * qkv[f * 768 + 512 + h * 32 + d];
        part[t] = acc;
    }
    __syncthreads();
    if (t < 256) srow[t] = (part[t] + part[256 + t] + part[512 + t] + part[768 + t]) * ssum[t >> 5];
    __syncthreads();
    // ---- oproj: 256 outputs x 4 chunks of 64 ----
    {
        int o = t & 255, c = t >> 8;
        float acc = 0.f;
        #pragma unroll 8
        for (int i = c * 64; i < c * 64 + 64; i++) acc += srow[i] * opwT[(size_t)i * 256 + o];
        part[t] = acc;
    }
    __syncthreads();
    // ---- norm2 -> x1, xq ----
    {
        float acc = 0.f;
        if (t < 256) acc = part[t] + part[256 + t] + part[512 + t] + part[768 + t] + opb[t] + tgt[e * 256 + t];
        float mean = block_sum256w(acc, red) * (1.f / 256.f);
        float d0 = acc - mean;
        float var = block_sum256w((t < 256) ? d0 * d0 : 0.f, red) * (1.f / 256.f);
        if (t < 256) {
            float xln = d0 * rsqrtf(var + 1e-5f) * n2w[t] + n2b[t];
            x1[e * 256 + t] = xln;
            xq[t] = xln + qpos[e * 256 + t];
        }
    }
    // ---- pos-encode for 3 points (pe3 overlaps dead sq/sS; barriers inside
    //      norm2's block_sum separate the phases) ----
    #pragma unroll
    for (int rep = 0; rep < 2; rep++) {
        int idx = rep * 1024 + t;
        if (idx < 1152) {
            int j = idx / 384, w = idx - j * 384;
            float pxs[3], pys[3], fmx, fmy, cxf, cyf;
            edge_geom(ec, e, j, pxs, pys, fmx, fmy, cxf, cyf);
            int jj = w >> 7, tt = w & 127, i = tt & 63, kk = i >> 1;
            float invd = __expf(-(float)kk * (9.210340371976184f / 32.f));  // 10000^(-kk/32)
            float vv = (tt < 64) ? pys[jj] : pxs[jj];
            float pp = vv * invd;
            pe3[idx] = (i & 1) ? __cosf(pp) : __sinf(pp);
        }
    }
    if (t < 3) {
        int j = t, n = 3 * e + j;
        float pxs[3], pys[3], fmx, fmy, cxf, cyf;
        edge_geom(ec, e, j, pxs, pys, fmx, fmy, cxf, cyf);
        refxy[n * 2 + 0] = (cxf - fmx) * (1.f / 256.f);
        refxy[n * 2 + 1] = (cyf - fmy) * (1.f / 256.f);
        lxly[n * 8 + 0] = (int)rintf(fmx * 0.125f);
        lxly[n * 8 + 1] = (int)rintf(fmx * 0.0625f);
        lxly[n * 8 + 2] = (int)rintf(fmx * 0.03125f);
        lxly[n * 8 + 3] = (int)rintf(fmx * 0.015625f);
        lxly[n * 8 + 4] = (int)rintf(fmy * 0.125f);
        lxly[n * 8 + 5] = (int)rintf(fmy * 0.0625f);
        lxly[n * 8 + 6] = (int)rintf(fmy * 0.03125f);
        lxly[n * 8 + 7] = (int)rintf(fmy * 0.015625f);
    }
    __syncthreads();
    // ---- nq: K=640, 256 outs x 3 pts; 20 LDS-staged weight tiles of 32xK ----
    {
        float acc = 0.f;
        int o = t & 255, j = t >> 8;  // valid when t<768
        for (int tk = 0; tk < 20; tk++) {
            int k0 = tk * 32;
            const float4* s4 = (const float4*)(l0wT + (size_t)k0 * 256);
            float4* d4 = (float4*)wtile;
            d4[t] = s4[t];
            d4[1024 + t] = s4[1024 + t];
            __syncthreads();
            if (t < 768) {
                const float* inp = (tk < 8) ? (xq + k0) : (pe3 + j * 384 + (k0 - 256));
                #pragma unroll
                for (int k = 0; k < 32; k++)
                    acc += inp[k] * wtile[k * 256 + o];
            }
            __syncthreads();
        }
        if (t < 768) nrow3[j * 256 + o] = acc + l0b[o];
    }
    __syncthreads();
    // ---- off+attw via oawT: K=256, O=384, units (o,j)=1152; 8 tiles ----
    {
        int o1 = t % 384, j1 = t / 384;            // units 0..1023
        int o2 = 256 + (t & 127), j2 = 2;          // units 1024..1151 (t<128)
        float acc1 = 0.f, acc2 = 0.f;
        for (int tk = 0; tk < 8; tk++) {
            int k0 = tk * 32;
            const float4* s4 = (const float4*)(oawT + (size_t)k0 * 384);
            float4* d4 = (float4*)wtile;
            d4[t] = s4[t];
            d4[1024 + t] = s4[1024 + t];
            d4[2048 + t] = s4[2048 + t];
            __syncthreads();
            {
                const float* np1 = nrow3 + j1 * 256 + k0;
                #pragma unroll
                for (int k = 0; k < 32; k++)
                    acc1 += np1[k] * wtile[k * 384 + o1];
            }
            if (t < 128) {
                const float* np2 = nrow3 + j2 * 256 + k0;
                #pragma unroll
                for (int k = 0; k < 32; k++)
                    acc2 += np2[k] * wtile[k * 384 + o2];
            }
            __syncthreads();
        }
        {
            float b = (o1 < 256) ? offb[o1] : awb[o1 - 256];
            offatr[(size_t)(3 * e + j1) * 384 + o1] = acc1 + b;
        }
        if (t < 128) {
            offatr[(size_t)(3 * e + j2) * 384 + o2] = acc2 + awb[o2 - 256];
        }
    }
}

// ---------------- S3: deformable sampling (linearity-fused, valwT) ----------------
// grid N*H=3072, block 256
__global__ __launch_bounds__(256) void k_sample(const float* __restrict__ offatr,
                                                const float* __restrict__ refxy,
                                                const float* __restrict__ vr,
                                                const int* __restrict__ lxly,
                                                const float* __restrict__ src,
                                                const unsigned char* __restrict__ mask,
                                                const float* __restrict__ valwT,
                                                const float* __restrict__ valb,
                                                float* __restrict__ ca) {
    int n = blockIdx.x >> 3, h = blockIdx.x & 7, t = threadIdx.x;
    __shared__ float cw[64];
    __shared__ int cg[64];
    __shared__ float agg[256];
    __shared__ float sl[16], sred[2];
    __shared__ float pagg[32 * 8];
    if (t < 16) sl[t] = offatr[n * 384 + 256 + h * 16 + t];
    __syncthreads();
    if (t == 0) {
        float m = -1e30f;
        for (int i = 0; i < 16; i++) m = fmaxf(m, sl[i]);
        float s = 0.f;
        for (int i = 0; i < 16; i++) s += __expf(sl[i] - m);
        sred[0] = m; sred[1] = 1.f / s;
    }
    __syncthreads();
    if (t < 64) {
        int l = t >> 4, pp = (t >> 2) & 3, tap = t & 3;
        int s = 32 >> l;
        int wl = 256 >> l;
        const int img_starts[4] = {0, 65536, 81920, 86016};
        float a = __expf(sl[l * 4 + pp] - sred[0]) * sred[1];
        float slv = (float)s;
        float gx = refxy[n * 2 + 0] * vr[l * 2 + 0] + offatr[n * 384 + h * 32 + l * 8 + pp * 2 + 0] / slv;
        float gy = refxy[n * 2 + 1] * vr[l * 2 + 1] + offatr[n * 384 + h * 32 + l * 8 + pp * 2 + 1] / slv;
        float px = gx * slv - 0.5f, py = gy * slv - 0.5f;
        float x0 = floorf(px), y0 = floorf(py);
        float fx = px - x0, fy = py - y0;
        int xi = (int)x0 + (tap & 1), yi = (int)y0 + (tap >> 1);
        float wt = ((tap & 1) ? fx : (1.f - fx)) * ((tap >> 1) ? fy : (1.f - fy));
        int g = -1;
        if (xi >= 0 && xi < s && yi >= 0 && yi < s) {
            int col = lxly[n * 8 + l] + xi;
            int row = lxly[n * 8 + 4 + l] + yi;
            g = img_starts[l] + row * wl + col;
            if (mask[g]) g = -1;  // masked rows zeroed (incl. bias)
        }
        cw[t] = a * wt;
        cg[t] = g;
    }
    __syncthreads();
    float acc = 0.f, csum = 0.f;
    for (int tp = 0; tp < 64; tp++) {
        int g = cg[tp];
        if (g >= 0) {
            acc += cw[tp] * src[(size_t)g * 256 + t];
            csum += cw[tp];
        }
    }
    agg[t] = acc;
    __syncthreads();
    {
        int o = t & 31, qtr = t >> 5;
        float pv = 0.f;
        #pragma unroll
        for (int i = 0; i < 32; i++) {
            int ii = qtr * 32 + i;
            pv += agg[ii] * valwT[(size_t)ii * 256 + h * 32 + o];
        }
        pagg[o * 8 + qtr] = pv;
    }
    __syncthreads();
    if (t < 32) {
        float o = 0.f;
        for (int qtr = 0; qtr < 8; qtr++) o += pagg[t * 8 + qtr];
        ca[n * 256 + h * 32 + t] = o + csum * valb[h * 32 + t];
    }
}

// ---------------- S4: pool + oproj + norm1 + ffn1 + ffn2 + norm3 ----------------
// grid 128 (per edge), block 1024
__global__ __launch_bounds__(1024) void k_tail(const float* __restrict__ ca,
                                               const float* __restrict__ x1,
                                               const float* __restrict__ ojwT,
                                               const float* __restrict__ ojb,
                                               const float* __restrict__ n1w,
                                               const float* __restrict__ n1b,
                                               const float* __restrict__ l1wT,
                                               const float* __restrict__ l1b,
                                               const float* __restrict__ l2wT,
                                               const float* __restrict__ l2b,
                                               const float* __restrict__ n3w,
                                               const float* __restrict__ n3b,
                                               float* __restrict__ out) {
    int e = blockIdx.x, t = threadIdx.x;
    __shared__ float row[256], red[256], x2s[256], h1s[1024], part[1024];
    if (t < 256)
        row[t] = (ca[(3 * e) * 256 + t] + ca[(3 * e + 1) * 256 + t] + ca[(3 * e + 2) * 256 + t]) * (1.f / 3.f);
    __syncthreads();
    // oproj: 256 outputs x 4 chunks of 64
    {
        int o = t & 255, c = t >> 8;
        float acc = 0.f;
        #pragma unroll 8
        for (int i = c * 64; i < c * 64 + 64; i++) acc += row[i] * ojwT[(size_t)i * 256 + o];
        part[t] = acc;
    }
    __syncthreads();
    // norm1
    {
        float acc = 0.f;
        if (t < 256) acc = part[t] + part[256 + t] + part[512 + t] + part[768 + t] + ojb[t] + x1[e * 256 + t];
        float mean = block_sum256w(acc, red) * (1.f / 256.f);
        float d0 = acc - mean;
        float var = block_sum256w((t < 256) ? d0 * d0 : 0.f, red) * (1.f / 256.f);
        if (t < 256) x2s[t] = d0 * rsqrtf(var + 1e-5f) * n1w[t] + n1b[t];
    }
    __syncthreads();
    // ffn1: one output per thread
    {
        float acc = l1b[t];
        #pragma unroll 8
        for (int i = 0; i < 256; i++) acc += x2s[i] * l1wT[(size_t)i * 1024 + t];
        h1s[t] = fmaxf(acc, 0.f);
    }
    __syncthreads();
    // ffn2: 256 outputs x 4 chunks of 256
    {
        int o = t & 255, c = t >> 8;
        float acc = 0.f;
        #pragma unroll 8
        for (int i = c * 256; i < c * 256 + 256; i++) acc += h1s[i] * l2wT[(size_t)i * 256 + o];
        part[t] = acc;
    }
    __syncthreads();
    // norm3 -> out
    {
        float acc = 0.f;
        if (t < 256) acc = part[t] + part[256 + t] + part[512 + t] + part[768 + t] + l2b[t] + x2s[t];
        float mean = block_sum256w(acc, red) * (1.f / 256.f);
        float d0 = acc - mean;
        float var = block_sum256w((t < 256) ? d0 * d0 : 0.f, red) * (1.f / 256.f);
        if (t < 256) out[e * 256 + t] = d0 * rsqrtf(var + 1e-5f) * n3w[t] + n3b[t];
    }
}

extern "C" void kernel_launch(void* const* d_in, const int* in_sizes, int n_in,
                              void* d_out, int out_size, void* d_ws, size_t ws_size,
                              hipStream_t stream) {
    (void)in_sizes; (void)n_in; (void)out_size; (void)ws_size;
    const float* tgt  = (const float*)d_in[0];
    const float* qpos = (const float*)d_in[1];
    const float* ec   = (const float*)d_in[2];
    const float* src  = (const float*)d_in[3];
    const unsigned char* mask = (const unsigned char*)d_in[4];
    const float* vr   = (const float*)d_in[5];
    const float* ipw  = (const float*)d_in[6];
    const float* ipb  = (const float*)d_in[7];
    const float* opw  = (const float*)d_in[8];
    const float* opb  = (const float*)d_in[9];
    const float* n1w  = (const float*)d_in[10];
    const float* n1b  = (const float*)d_in[11];
    const float* n2w  = (const float*)d_in[12];
    const float* n2b  = (const float*)d_in[13];
    const float* n3w  = (const float*)d_in[14];
    const float* n3b  = (const float*)d_in[15];
    const float* l0w  = (const float*)d_in[16];
    const float* l0b  = (const float*)d_in[17];
    const float* l1w  = (const float*)d_in[18];
    const float* l1b  = (const float*)d_in[19];
    const float* l2w  = (const float*)d_in[20];
    const float* l2b  = (const float*)d_in[21];
    const float* offw = (const float*)d_in[22];
    const float* offb = (const float*)d_in[23];
    const float* aww  = (const float*)d_in[24];
    const float* awb  = (const float*)d_in[25];
    const float* valw = (const float*)d_in[26];
    const float* valb = (const float*)d_in[27];
    const float* ojw  = (const float*)d_in[28];
    const float* ojb  = (const float*)d_in[29];

    float* ws     = (float*)d_ws;
    float* qkv    = ws;               // 98304
    float* x1     = ws + 98304;       // 32768
    float* offatr = ws + 131072;      // 147456
    float* ca     = ws + 278528;      // 98304
    float* refxy  = ws + 376832;      // 768
    int*   lxly   = (int*)(ws + 377600); // 3072 ints
    float* opwT   = ws + 380672;      // 65536
    float* ojwT   = ws + 446208;      // 65536
    float* valwT  = ws + 511744;      // 65536
    float* l1wT   = ws + 577280;      // 262144
    float* l2wT   = ws + 839424;      // 262144
    float* l0wT   = ws + 1101568;     // 163840
    float* oawT   = ws + 1265408;     // 98304

    k_prep<<<1152, 256, 0, stream>>>(tgt, qpos, ipw, ipb, opw, ojw, valw, l1w, l2w,
                                     l0w, offw, aww,
                                     qkv, opwT, ojwT, valwT, l1wT, l2wT, l0wT, oawT);
    k_edge<<<128, 1024, 0, stream>>>(qkv, tgt, qpos, opwT, opb, n2w, n2b, ec,
                                     l0wT, l0b, oawT, offb, awb,
                                     x1, offatr, refxy, lxly);
    k_sample<<<3072, 256, 0, stream>>>(offatr, refxy, vr, lxly, src, mask, valwT, valb, ca);
    k_tail<<<128, 1024, 0, stream>>>(ca, x1, ojwT, ojb, n1w, n1b, l1wT, l1b, l2wT, l2b, n3w, n3b, (float*)d_out);
}

// Round 9
// 300.892 us; speedup vs baseline: 3.7711x; 1.0770x over previous
//
#include <hip/hip_runtime.h>
#include <math.h>

// All inputs/outputs fp32 (verified R2).
// R9: k_edge per-point (grid 384, redundant attn per edge-triple) + bf16-packed
// weights (l0w, off|attw, l1w, l2w) halving staging/L2 traffic. R8: k_edge 55us,
// VALUBusy 8.7%, half the CUs idle at grid=128.

typedef unsigned int uint;

__device__ __forceinline__ float lo16(uint u) { return __uint_as_float(u << 16); }
__device__ __forceinline__ float hi16(uint u) { return __uint_as_float(u & 0xFFFF0000u); }
__device__ __forceinline__ uint bfr(float x) {  // fp32 -> bf16 bits, RNE
    uint u = __float_as_uint(x);
    return (u + 0x7FFFu + ((u >> 16) & 1u)) >> 16;
}

__device__ __forceinline__ float block_sum256w(float v, float* red) {
    int t = threadIdx.x;
    if (t < 256) red[t] = v;
    __syncthreads();
    for (int st = 128; st > 0; st >>= 1) {
        if (t < st) red[t] += red[t + st];
        __syncthreads();
    }
    float r = red[0]; __syncthreads();
    return r;
}

// ---- tiled GEMM unit (R4-verified): 64 rows x 8 outputs ----
template <int K, int MI, int MO>
__device__ void gemm_unit(const float* __restrict__ IN, const float* __restrict__ IN2,
                          const float* __restrict__ W, const float* __restrict__ B,
                          float* __restrict__ OUT, int O, int OG, int u, float* smem) {
    constexpr int KC = 128;
    constexpr int LDT = KC + 4;
    float* tile = smem;
    int og = u % OG, rg = u / OG;
    int o0 = og * 8, r0 = rg * 64;
    int t = threadIdx.x;
    int r = t & 63;
    int ol = __builtin_amdgcn_readfirstlane(t >> 6);
    int oa = o0 + ol, ob = o0 + 4 + ol;
    const float* Wa = W + (size_t)oa * K;
    const float* Wb = W + (size_t)ob * K;
    float Ba = B[oa], Bb = B[ob];
    float acca = 0.f, accb = 0.f;
    for (int c = 0; c < K / KC; c++) {
        for (int idx = t; idx < 64 * KC; idx += 256) {
            int rr = idx >> 7, ii = idx & (KC - 1);
            int row = r0 + rr, col = c * KC + ii;
            float v;
            if (MI == 0) {
                v = IN[(size_t)row * K + col];
            } else {
                float tv = IN[row * 256 + col];
                v = (o0 < 512) ? tv + IN2[row * 256 + col] : tv;
            }
            tile[rr * LDT + ii] = v;
        }
        __syncthreads();
        const float4* wa4 = (const float4*)(Wa + c * KC);
        const float4* wb4 = (const float4*)(Wb + c * KC);
        const float4* trow = (const float4*)(tile + r * LDT);
        #pragma unroll
        for (int i4 = 0; i4 < KC / 4; i4++) {
            float4 x4 = trow[i4];
            float4 a4 = wa4[i4];
            float4 b4 = wb4[i4];
            acca += x4.x * a4.x; acca += x4.y * a4.y;
            acca += x4.z * a4.z; acca += x4.w * a4.w;
            accb += x4.x * b4.x; accb += x4.y * b4.y;
            accb += x4.z * b4.z; accb += x4.w * b4.w;
        }
        __syncthreads();
    }
    acca += Ba; accb += Bb;
    if (MO == 2) {
        if (oa < 256) acca *= 0.17677669529663687f;
        if (ob < 256) accb *= 0.17677669529663687f;
    }
    OUT[(size_t)(r0 + r) * O + oa] = acca;
    OUT[(size_t)(r0 + r) * O + ob] = accb;
}

// ---- fp32 transpose unit: out[c*256 + r] = in[r][c] (R,C mult of 32) ----
__device__ void transpose_unit(const float* __restrict__ in, float* __restrict__ out,
                               int R, int C, int u, float* smem) {
    int TC = C >> 5;
    int tc = u % TC, tr = u / TC;
    int t = threadIdx.x;
    int lr = t >> 5, lc = t & 31;
    #pragma unroll
    for (int rr = 0; rr < 32; rr += 8)
        smem[(rr + lr) * 33 + lc] = in[(size_t)(tr * 32 + rr + lr) * C + tc * 32 + lc];
    __syncthreads();
    #pragma unroll
    for (int rr = 0; rr < 32; rr += 8)
        out[(size_t)(tc * 32 + rr + lr) * R + tr * 32 + lc] = smem[lc * 33 + rr + lr];
    __syncthreads();
}

// ---- transpose+bf16-pack: P[(k2)*S + F + r] = pack(in[r][2k2], in[r][2k2+1]) ----
__device__ void tpack_unit(const float* __restrict__ in, uint* __restrict__ P,
                           int C, int S, int F, int u, float* smem) {
    int TC = C >> 5;
    int tc = u % TC, tr = u / TC;
    int t = threadIdx.x;
    int lr = t >> 5, lc = t & 31;
    #pragma unroll
    for (int rr = 0; rr < 32; rr += 8)
        smem[(rr + lr) * 33 + lc] = in[(size_t)(tr * 32 + rr + lr) * C + tc * 32 + lc];
    __syncthreads();
    #pragma unroll
    for (int rep = 0; rep < 2; rep++) {
        int idx = rep * 256 + t;
        int c2 = idx >> 5, r = idx & 31;
        uint w0 = bfr(smem[r * 33 + 2 * c2]);
        uint w1 = bfr(smem[r * 33 + 2 * c2 + 1]);
        P[(size_t)(tc * 16 + c2) * S + F + tr * 32 + r] = (w1 << 16) | w0;
    }
    __syncthreads();
}

// ---------------- S1: qkv gemm + weight transposes/packs ----------------
// grid 1152, block 256
__global__ __launch_bounds__(256) void k_prep(const float* __restrict__ tgt,
                                              const float* __restrict__ qpos,
                                              const float* __restrict__ ipw,
                                              const float* __restrict__ ipb,
                                              const float* __restrict__ opw,
                                              const float* __restrict__ ojw,
                                              const float* __restrict__ valw,
                                              const float* __restrict__ l1w,
                                              const float* __restrict__ l2w,
                                              const float* __restrict__ l0w,
                                              const float* __restrict__ offw,
                                              const float* __restrict__ aww,
                                              float* __restrict__ qkv,
                                              float* __restrict__ opwT,
                                              float* __restrict__ ojwT,
                                              float* __restrict__ valwT,
                                              uint* __restrict__ Pl1,
                                              uint* __restrict__ Pl2,
                                              uint* __restrict__ Pl0,
                                              uint* __restrict__ Poaw) {
    __shared__ __align__(16) float smem[8448];
    int u = blockIdx.x;
    if (u < 192)       gemm_unit<256, 1, 2>(tgt, qpos, ipw, ipb, qkv, 768, 96, u, smem);
    else if (u < 256)  transpose_unit(opw, opwT, 256, 256, u - 192, smem);
    else if (u < 320)  transpose_unit(ojw, ojwT, 256, 256, u - 256, smem);
    else if (u < 384)  transpose_unit(valw, valwT, 256, 256, u - 320, smem);
    else if (u < 640)  tpack_unit(l1w, Pl1, 256, 1024, 0, u - 384, smem);
    else if (u < 896)  tpack_unit(l2w, Pl2, 1024, 256, 0, u - 640, smem);
    else if (u < 1056) tpack_unit(l0w, Pl0, 640, 256, 0, u - 896, smem);
    else if (u < 1120) tpack_unit(offw, Poaw, 256, 384, 0, u - 1056, smem);
    else               tpack_unit(aww, Poaw, 256, 384, 256, u - 1120, smem);
}

// ---- geometry for edge e, point j ----
__device__ __forceinline__ void edge_geom(const float* __restrict__ ec, int e, int j,
                                          float* pxs, float* pys,
                                          float& fminx, float& fminy,
                                          float& cxf, float& cyf) {
    float ax = ec[e * 4 + 0], ay = ec[e * 4 + 1];
    float bx = ec[e * 4 + 2], by = ec[e * 4 + 3];
    float dx = bx - ax, dy = by - ay;
    float tj = 0.5f * (float)j;
    float ptx = __fadd_rn(ax, __fmul_rn(tj, dx));
    float pty = __fadd_rn(ay, __fmul_rn(tj, dy));
    cxf = floorf(ptx); cyf = floorf(pty);
    int minx = max((int)cxf - 128, 0); if (minx + 256 > 2048) minx = 2048 - 256;
    int miny = max((int)cyf - 128, 0); if (miny + 256 > 2048) miny = 2048 - 256;
    fminx = (float)minx; fminy = (float)miny;
    float tlx, thx, tly, thy;
    if (dx == 0.f) { tlx = 0.f; thx = 1.f; }
    else { float u1 = (fminx - ax) / dx, u2 = (fminx + 256.f - ax) / dx; tlx = fminf(u1, u2); thx = fmaxf(u1, u2); }
    if (dy == 0.f) { tly = 0.f; thy = 1.f; }
    else { float u1 = (fminy - ay) / dy, u2 = (fminy + 256.f - ay) / dy; tly = fminf(u1, u2); thy = fmaxf(u1, u2); }
    float t0 = fmaxf(fmaxf(tlx, tly), 0.f);
    float t1 = fmaxf(fminf(fminf(thx, thy), 1.f), t0);
    pxs[0] = __fadd_rn(ax, __fmul_rn(t0, dx)); pys[0] = __fadd_rn(ay, __fmul_rn(t0, dy));
    pxs[1] = __fadd_rn(ax, __fmul_rn(t1, dx)); pys[1] = __fadd_rn(ay, __fmul_rn(t1, dy));
    pxs[2] = cxf; pys[2] = cyf;
}

// ---------------- S2: per-POINT (grid 384): attn(redundant)+oproj+norm2+pe+nq+offaw ----
// LDS pool (floats unless noted), 14208 slots = 56832 B:
//  xq@0(256) persists
//  phase A: sq@256 sS@512(1024) smax@1536(8) ssum@1544(8) srow@1552(256)
//           part@1808(1024) red@2832(256)
//  phase B: pe@256(384) nrow@640(256) partial@896(1024) wt@1920(12288 uints)
__global__ __launch_bounds__(1024) void k_edge(const float* __restrict__ qkv,
                                               const float* __restrict__ tgt,
                                               const float* __restrict__ qpos,
                                               const float* __restrict__ opwT,
                                               const float* __restrict__ opb,
                                               const float* __restrict__ n2w,
                                               const float* __restrict__ n2b,
                                               const float* __restrict__ ec,
                                               const uint* __restrict__ Pl0,
                                               const float* __restrict__ l0b,
                                               const uint* __restrict__ Poaw,
                                               const float* __restrict__ offb,
                                               const float* __restrict__ awb,
                                               float* __restrict__ x1,
                                               float* __restrict__ offatr,
                                               float* __restrict__ refxy,
                                               int* __restrict__ lxly) {
    int n = blockIdx.x, t = threadIdx.x;
    int e = n / 3, j = n - e * 3;
    __shared__ __align__(16) float SH[14208];
    float* xq   = SH;
    float* sq   = SH + 256;
    float* sS   = SH + 512;
    float* smax = SH + 1536;
    float* ssum = SH + 1544;
    float* srow = SH + 1552;
    float* part = SH + 1808;
    float* red  = SH + 2832;
    float* pe    = SH + 256;    // phase B
    float* nrow  = SH + 640;
    float* partial = SH + 896;
    uint*  wt    = (uint*)(SH + 1920);
    // ---- attention (redundant across the 3 point-blocks of this edge) ----
    if (t < 256) sq[t] = qkv[e * 768 + t];
    __syncthreads();
    {
        int h = t >> 7, f = t & 127;
        const float* kf = qkv + f * 768 + 256 + h * 32;
        const float* qh = sq + h * 32;
        float s = 0.f;
        #pragma unroll 8
        for (int d = 0; d < 32; d++) s += qh[d] * kf[d];
        sS[t] = s;
    }
    __syncthreads();
    if (t < 8) {
        float m = -1e30f;
        for (int f = 0; f < 128; f++) m = fmaxf(m, sS[t * 128 + f]);
        smax[t] = m;
    }
    __syncthreads();
    sS[t] = __expf(sS[t] - smax[t >> 7]);
    __syncthreads();
    if (t < 8) {
        float s = 0.f;
        for (int f = 0; f < 128; f++) s += sS[t * 128 + f];
        ssum[t] = 1.f / s;
    }
    __syncthreads();
    {
        int o = t & 255, c = t >> 8, h = o >> 5, d = o & 31;
        float acc = 0.f;
        #pragma unroll 8
        for (int f = c * 32; f < c * 32 + 32; f++)
            acc += sS[h * 128 + f] * qkv[f * 768 + 512 + h * 32 + d];
        part[t] = acc;
    }
    __syncthreads();
    if (t < 256) srow[t] = (part[t] + part[256 + t] + part[512 + t] + part[768 + t]) * ssum[t >> 5];
    __syncthreads();
    // ---- oproj ----
    {
        int o = t & 255, c = t >> 8;
        float acc = 0.f;
        #pragma unroll 8
        for (int i = c * 64; i < c * 64 + 64; i++) acc += srow[i] * opwT[(size_t)i * 256 + o];
        part[t] = acc;
    }
    __syncthreads();
    // ---- norm2 -> x1 (j==0 only), xq ----
    {
        float acc = 0.f;
        if (t < 256) acc = part[t] + part[256 + t] + part[512 + t] + part[768 + t] + opb[t] + tgt[e * 256 + t];
        float mean = block_sum256w(acc, red) * (1.f / 256.f);
        float d0 = acc - mean;
        float var = block_sum256w((t < 256) ? d0 * d0 : 0.f, red) * (1.f / 256.f);
        if (t < 256) {
            float xln = d0 * rsqrtf(var + 1e-5f) * n2w[t] + n2b[t];
            if (j == 0) x1[e * 256 + t] = xln;
            xq[t] = xln + qpos[e * 256 + t];
        }
    }
    // ---- pos-encode: own point only (384 elems; aliases dead sq/sS) ----
    if (t < 384) {
        float pxs[3], pys[3], fmx, fmy, cxf, cyf;
        edge_geom(ec, e, j, pxs, pys, fmx, fmy, cxf, cyf);
        int jj = t >> 7, tt = t & 127, i = tt & 63, kk = i >> 1;
        float invd = __expf(-(float)kk * (9.210340371976184f / 32.f));  // 10000^(-kk/32)
        float vv = (tt < 64) ? pys[jj] : pxs[jj];
        float pp = vv * invd;
        pe[t] = (i & 1) ? __cosf(pp) : __sinf(pp);
    }
    if (t == 0) {
        float pxs[3], pys[3], fmx, fmy, cxf, cyf;
        edge_geom(ec, e, j, pxs, pys, fmx, fmy, cxf, cyf);
        refxy[n * 2 + 0] = (cxf - fmx) * (1.f / 256.f);
        refxy[n * 2 + 1] = (cyf - fmy) * (1.f / 256.f);
        lxly[n * 8 + 0] = (int)rintf(fmx * 0.125f);
        lxly[n * 8 + 1] = (int)rintf(fmx * 0.0625f);
        lxly[n * 8 + 2] = (int)rintf(fmx * 0.03125f);
        lxly[n * 8 + 3] = (int)rintf(fmx * 0.015625f);
        lxly[n * 8 + 4] = (int)rintf(fmy * 0.125f);
        lxly[n * 8 + 5] = (int)rintf(fmy * 0.0625f);
        lxly[n * 8 + 6] = (int)rintf(fmy * 0.03125f);
        lxly[n * 8 + 7] = (int)rintf(fmy * 0.015625f);
    }
    __syncthreads();
    // ---- nq: K=640, 256 outs; 10 tiles of 64k (32 packed rows x 256) ----
    {
        int o = t & 255, kc = t >> 8;
        float acc = 0.f;
        for (int tk = 0; tk < 10; tk++) {
            const uint4* s4 = (const uint4*)(Pl0 + (size_t)tk * 8192);
            uint4* d4 = (uint4*)wt;
            d4[t] = s4[t];
            d4[1024 + t] = s4[1024 + t];
            __syncthreads();
            const float* inb = (tk < 4) ? (xq + tk * 64) : (pe + tk * 64 - 256);
            #pragma unroll
            for (int kk = 0; kk < 8; kk++) {
                uint u = wt[(kc * 8 + kk) * 256 + o];
                acc += inb[(kc * 8 + kk) * 2] * lo16(u);
                acc += inb[(kc * 8 + kk) * 2 + 1] * hi16(u);
            }
            __syncthreads();
        }
        partial[t] = acc;
    }
    __syncthreads();
    if (t < 256) nrow[t] = partial[t] + partial[256 + t] + partial[512 + t] + partial[768 + t] + l0b[t];
    __syncthreads();
    // ---- off+attw: K=256, O=384; 4 tiles of 64k (32 packed rows x 384) ----
    {
        int o = t % 384, kc = t / 384;  // valid for t<768
        float acc = 0.f;
        for (int tk = 0; tk < 4; tk++) {
            const uint4* s4 = (const uint4*)(Poaw + (size_t)tk * 12288);
            uint4* d4 = (uint4*)wt;
            d4[t] = s4[t];
            d4[1024 + t] = s4[1024 + t];
            d4[2048 + t] = s4[2048 + t];
            __syncthreads();
            if (t < 768) {
                const float* inb = nrow + tk * 64 + kc * 32;
                #pragma unroll
                for (int kk = 0; kk < 16; kk++) {
                    uint u = wt[(kc * 16 + kk) * 384 + o];
                    acc += inb[kk * 2] * lo16(u);
                    acc += inb[kk * 2 + 1] * hi16(u);
                }
            }
            __syncthreads();
        }
        if (t < 768) partial[t] = acc;
    }
    __syncthreads();
    if (t < 384) {
        float b = (t < 256) ? offb[t] : awb[t - 256];
        offatr[(size_t)n * 384 + t] = partial[t] + partial[384 + t] + b;
    }
}

// ---------------- S3: deformable sampling (linearity-fused, valwT) ----------------
// grid N*H=3072, block 256
__global__ __launch_bounds__(256) void k_sample(const float* __restrict__ offatr,
                                                const float* __restrict__ refxy,
                                                const float* __restrict__ vr,
                                                const int* __restrict__ lxly,
                                                const float* __restrict__ src,
                                                const unsigned char* __restrict__ mask,
                                                const float* __restrict__ valwT,
                                                const float* __restrict__ valb,
                                                float* __restrict__ ca) {
    int n = blockIdx.x >> 3, h = blockIdx.x & 7, t = threadIdx.x;
    __shared__ float cw[64];
    __shared__ int cg[64];
    __shared__ float agg[256];
    __shared__ float sl[16], sred[2];
    __shared__ float pagg[32 * 8];
    if (t < 16) sl[t] = offatr[n * 384 + 256 + h * 16 + t];
    __syncthreads();
    if (t == 0) {
        float m = -1e30f;
        for (int i = 0; i < 16; i++) m = fmaxf(m, sl[i]);
        float s = 0.f;
        for (int i = 0; i < 16; i++) s += __expf(sl[i] - m);
        sred[0] = m; sred[1] = 1.f / s;
    }
    __syncthreads();
    if (t < 64) {
        int l = t >> 4, pp = (t >> 2) & 3, tap = t & 3;
        int s = 32 >> l;
        int wl = 256 >> l;
        const int img_starts[4] = {0, 65536, 81920, 86016};
        float a = __expf(sl[l * 4 + pp] - sred[0]) * sred[1];
        float slv = (float)s;
        float gx = refxy[n * 2 + 0] * vr[l * 2 + 0] + offatr[n * 384 + h * 32 + l * 8 + pp * 2 + 0] / slv;
        float gy = refxy[n * 2 + 1] * vr[l * 2 + 1] + offatr[n * 384 + h * 32 + l * 8 + pp * 2 + 1] / slv;
        float px = gx * slv - 0.5f, py = gy * slv - 0.5f;
        float x0 = floorf(px), y0 = floorf(py);
        float fx = px - x0, fy = py - y0;
        int xi = (int)x0 + (tap & 1), yi = (int)y0 + (tap >> 1);
        float wtt = ((tap & 1) ? fx : (1.f - fx)) * ((tap >> 1) ? fy : (1.f - fy));
        int g = -1;
        if (xi >= 0 && xi < s && yi >= 0 && yi < s) {
            int col = lxly[n * 8 + l] + xi;
            int row = lxly[n * 8 + 4 + l] + yi;
            g = img_starts[l] + row * wl + col;
            if (mask[g]) g = -1;  // masked rows zeroed (incl. bias)
        }
        cw[t] = a * wtt;
        cg[t] = g;
    }
    __syncthreads();
    float acc = 0.f, csum = 0.f;
    for (int tp = 0; tp < 64; tp++) {
        int g = cg[tp];
        if (g >= 0) {
            acc += cw[tp] * src[(size_t)g * 256 + t];
            csum += cw[tp];
        }
    }
    agg[t] = acc;
    __syncthreads();
    {
        int o = t & 31, qtr = t >> 5;
        float pv = 0.f;
        #pragma unroll
        for (int i = 0; i < 32; i++) {
            int ii = qtr * 32 + i;
            pv += agg[ii] * valwT[(size_t)ii * 256 + h * 32 + o];
        }
        pagg[o * 8 + qtr] = pv;
    }
    __syncthreads();
    if (t < 32) {
        float o = 0.f;
        for (int qtr = 0; qtr < 8; qtr++) o += pagg[t * 8 + qtr];
        ca[n * 256 + h * 32 + t] = o + csum * valb[h * 32 + t];
    }
}

// ---------------- S4: pool + oproj + norm1 + ffn1 + ffn2 + norm3 ----------------
// grid 128 (per edge), block 1024; ffn weights bf16-packed
__global__ __launch_bounds__(1024) void k_tail(const float* __restrict__ ca,
                                               const float* __restrict__ x1,
                                               const float* __restrict__ ojwT,
                                               const float* __restrict__ ojb,
                                               const float* __restrict__ n1w,
                                               const float* __restrict__ n1b,
                                               const uint* __restrict__ Pl1,
                                               const float* __restrict__ l1b,
                                               const uint* __restrict__ Pl2,
                                               const float* __restrict__ l2b,
                                               const float* __restrict__ n3w,
                                               const float* __restrict__ n3b,
                                               float* __restrict__ out) {
    int e = blockIdx.x, t = threadIdx.x;
    __shared__ float row[256], red[256], x2s[256], h1s[1024], part[1024];
    if (t < 256)
        row[t] = (ca[(3 * e) * 256 + t] + ca[(3 * e + 1) * 256 + t] + ca[(3 * e + 2) * 256 + t]) * (1.f / 3.f);
    __syncthreads();
    // oproj: 256 outputs x 4 chunks of 64
    {
        int o = t & 255, c = t >> 8;
        float acc = 0.f;
        #pragma unroll 8
        for (int i = c * 64; i < c * 64 + 64; i++) acc += row[i] * ojwT[(size_t)i * 256 + o];
        part[t] = acc;
    }
    __syncthreads();
    // norm1
    {
        float acc = 0.f;
        if (t < 256) acc = part[t] + part[256 + t] + part[512 + t] + part[768 + t] + ojb[t] + x1[e * 256 + t];
        float mean = block_sum256w(acc, red) * (1.f / 256.f);
        float d0 = acc - mean;
        float var = block_sum256w((t < 256) ? d0 * d0 : 0.f, red) * (1.f / 256.f);
        if (t < 256) x2s[t] = d0 * rsqrtf(var + 1e-5f) * n1w[t] + n1b[t];
    }
    __syncthreads();
    // ffn1: one output per thread, packed K=256 (128 uints)
    {
        float acc = l1b[t];
        #pragma unroll 8
        for (int k2 = 0; k2 < 128; k2++) {
            uint u = Pl1[(size_t)k2 * 1024 + t];
            acc += x2s[2 * k2] * lo16(u);
            acc += x2s[2 * k2 + 1] * hi16(u);
        }
        h1s[t] = fmaxf(acc, 0.f);
    }
    __syncthreads();
    // ffn2: 256 outputs x 4 chunks of 128 packed
    {
        int o = t & 255, c = t >> 8;
        float acc = 0.f;
        #pragma unroll 8
        for (int k2 = c * 128; k2 < c * 128 + 128; k2++) {
            uint u = Pl2[(size_t)k2 * 256 + o];
            acc += h1s[2 * k2] * lo16(u);
            acc += h1s[2 * k2 + 1] * hi16(u);
        }
        part[t] = acc;
    }
    __syncthreads();
    // norm3 -> out
    {
        float acc = 0.f;
        if (t < 256) acc = part[t] + part[256 + t] + part[512 + t] + part[768 + t] + l2b[t] + x2s[t];
        float mean = block_sum256w(acc, red) * (1.f / 256.f);
        float d0 = acc - mean;
        float var = block_sum256w((t < 256) ? d0 * d0 : 0.f, red) * (1.f / 256.f);
        if (t < 256) out[e * 256 + t] = d0 * rsqrtf(var + 1e-5f) * n3w[t] + n3b[t];
    }
}

extern "C" void kernel_launch(void* const* d_in, const int* in_sizes, int n_in,
                              void* d_out, int out_size, void* d_ws, size_t ws_size,
                              hipStream_t stream) {
    (void)in_sizes; (void)n_in; (void)out_size; (void)ws_size;
    const float* tgt  = (const float*)d_in[0];
    const float* qpos = (const float*)d_in[1];
    const float* ec   = (const float*)d_in[2];
    const float* src  = (const float*)d_in[3];
    const unsigned char* mask = (const unsigned char*)d_in[4];
    const float* vr   = (const float*)d_in[5];
    const float* ipw  = (const float*)d_in[6];
    const float* ipb  = (const float*)d_in[7];
    const float* opw  = (const float*)d_in[8];
    const float* opb  = (const float*)d_in[9];
    const float* n1w  = (const float*)d_in[10];
    const float* n1b  = (const float*)d_in[11];
    const float* n2w  = (const float*)d_in[12];
    const float* n2b  = (const float*)d_in[13];
    const float* n3w  = (const float*)d_in[14];
    const float* n3b  = (const float*)d_in[15];
    const float* l0w  = (const float*)d_in[16];
    const float* l0b  = (const float*)d_in[17];
    const float* l1w  = (const float*)d_in[18];
    const float* l1b  = (const float*)d_in[19];
    const float* l2w  = (const float*)d_in[20];
    const float* l2b  = (const float*)d_in[21];
    const float* offw = (const float*)d_in[22];
    const float* offb = (const float*)d_in[23];
    const float* aww  = (const float*)d_in[24];
    const float* awb  = (const float*)d_in[25];
    const float* valw = (const float*)d_in[26];
    const float* valb = (const float*)d_in[27];
    const float* ojw  = (const float*)d_in[28];
    const float* ojb  = (const float*)d_in[29];

    float* ws     = (float*)d_ws;
    float* qkv    = ws;                   // 98304
    float* x1     = ws + 98304;           // 32768
    float* offatr = ws + 131072;          // 147456
    float* ca     = ws + 278528;          // 98304
    float* refxy  = ws + 376832;          // 768
    int*   lxly   = (int*)(ws + 377600);  // 3072
    float* opwT   = ws + 380672;          // 65536
    float* ojwT   = ws + 446208;          // 65536
    float* valwT  = ws + 511744;          // 65536
    uint*  Pl1    = (uint*)(ws + 577280); // 131072
    uint*  Pl2    = (uint*)(ws + 708352); // 131072
    uint*  Pl0    = (uint*)(ws + 839424); // 81920
    uint*  Poaw   = (uint*)(ws + 921344); // 49152

    k_prep<<<1152, 256, 0, stream>>>(tgt, qpos, ipw, ipb, opw, ojw, valw, l1w, l2w,
                                     l0w, offw, aww,
                                     qkv, opwT, ojwT, valwT, Pl1, Pl2, Pl0, Poaw);
    k_edge<<<384, 1024, 0, stream>>>(qkv, tgt, qpos, opwT, opb, n2w, n2b, ec,
                                     Pl0, l0b, Poaw, offb, awb,
                                     x1, offatr, refxy, lxly);
    k_sample<<<3072, 256, 0, stream>>>(offatr, refxy, vr, lxly, src, mask, valwT, valb, ca);
    k_tail<<<128, 1024, 0, stream>>>(ca, x1, ojwT, ojb, n1w, n1b, Pl1, l1b, Pl2, l2b, n3w, n3b, (float*)d_out);
}